// Round 2
// baseline (677.033 us; speedup 1.0000x reference)
//
// SlotAttention fused forward for MI355X (gfx950) — round 2.
// Changes vs r1: (a) iteration-0 big pass writes a bf16 feature cache + per-token
// LN stats; iterations 1-2 read bf16 (half traffic, no cvt/stats VALU).
// (b) all small GEMMs use pre-transposed bf16 weights (one prep kernel) so weight
// reads are coalesced b64 loads from L2 — no LDS staging needed.
// (c) small stages fused 7 kernels/iter -> 3 (big, K2=upd+GRU+LN, K3=MLP+residual+
// next-iter LN/q/u). 11 launches total vs 21.
#include <hip/hip_runtime.h>
#include <cstdint>
#include <cstddef>

#define BB    16
#define NTOK  16384
#define KS    16
#define DD    256
#define FEATN 256
#define NBLK  32
#define LN_EPS 1e-5f

typedef float        float4v __attribute__((ext_vector_type(4)));
typedef unsigned int uint4v  __attribute__((ext_vector_type(4)));
typedef unsigned int uint2v  __attribute__((ext_vector_type(2)));
typedef __bf16       bf16x8  __attribute__((ext_vector_type(8)));

__device__ __forceinline__ float bflo(unsigned u){ return __builtin_bit_cast(float, u << 16); }
__device__ __forceinline__ float bfhi(unsigned u){ return __builtin_bit_cast(float, u & 0xffff0000u); }
__device__ __forceinline__ unsigned short f2bf(float v){ __bf16 b = (__bf16)v; return __builtin_bit_cast(unsigned short, b); }

// ---------------------------------------------------------------- weight prep: bf16 (+transpose)
// Transposed matrices: dst[kin][out] = src[out][kin].  Wk is already [kin][out] -> cast only.
__global__ void prep_w_kernel(const float* __restrict__ Wv, const float* __restrict__ w_ih,
                              const float* __restrict__ w_hh, const float* __restrict__ W1,
                              const float* __restrict__ W2, const float* __restrict__ Wq,
                              const float* __restrict__ Wk,
                              unsigned short* __restrict__ Wv_t, unsigned short* __restrict__ wih_t,
                              unsigned short* __restrict__ whh_t, unsigned short* __restrict__ W1_t,
                              unsigned short* __restrict__ W2_t, unsigned short* __restrict__ Wq_t,
                              unsigned short* __restrict__ Wk_b)
{
  __shared__ float tile[64][65];
  const int t = blockIdx.x, tid = threadIdx.x;
  const float* src; unsigned short* dst; int R, C, base;
  if      (t < 16)  { src = Wv;   dst = Wv_t;  R = 256;  C = 256;  base = 0;   }
  else if (t < 64)  { src = w_ih; dst = wih_t; R = 768;  C = 256;  base = 16;  }
  else if (t < 112) { src = w_hh; dst = whh_t; R = 768;  C = 256;  base = 64;  }
  else if (t < 176) { src = W1;   dst = W1_t;  R = 1024; C = 256;  base = 112; }
  else if (t < 240) { src = W2;   dst = W2_t;  R = 256;  C = 1024; base = 176; }
  else if (t < 256) { src = Wq;   dst = Wq_t;  R = 256;  C = 256;  base = 240; }
  else {
    const int t2 = t - 256;
    for (int i = tid; i < 4096; i += 256) {
      const int idx = t2*4096 + i;
      Wk_b[idx] = f2bf(Wk[idx]);
    }
    return;
  }
  const int tt = t - base;
  const int tiles_r = R >> 6;
  const int r0 = (tt % tiles_r) * 64, c0 = (tt / tiles_r) * 64;
  const int j = tid & 63, i0 = (tid >> 6) * 16;
  for (int s = 0; s < 16; ++s)
    tile[i0 + s][j] = src[(size_t)(r0 + i0 + s)*C + c0 + j];
  __syncthreads();
  for (int s = 0; s < 16; ++s) {
    const int i = i0 + s;
    dst[(size_t)(c0 + i)*R + r0 + j] = f2bf(tile[j][i]);
  }
}

// ---------------------------------------------------------------- big fused attention pass
// MODE 0: read fp32 features, compute LN stats, write bf16 cache + stats.
// MODE 1: read bf16 cache + stats.
template<int MODE>
__launch_bounds__(256, 2)
__global__ void big_attn_kernel(const float* __restrict__ feat,
                                unsigned short* __restrict__ xb, float* __restrict__ stats,
                                const unsigned short* __restrict__ u_buf,
                                const float* __restrict__ su_buf,
                                const float* __restrict__ cb_buf,
                                float* __restrict__ P_part,
                                float* __restrict__ S_part,
                                float* __restrict__ R_part,
                                float* __restrict__ attn_out,
                                int last)
{
  __shared__ unsigned int xl[4][128*36];
  __shared__ float ssh[4][16];
  __shared__ float rsh[4][16];

  const int b   = blockIdx.x / NBLK;
  const int blk = blockIdx.x - b*NBLK;
  const int tid = threadIdx.x;
  const int w = tid >> 6;
  const int l = tid & 63;
  const int c = l & 15;
  const int g = l >> 4;

  bf16x8 ufrag[8];
  {
    const bf16x8* up = reinterpret_cast<const bf16x8*>(u_buf + (size_t)(b*KS + c)*DD);
    #pragma unroll
    for (int kk = 0; kk < 8; ++kk) ufrag[kk] = up[4*kk + g];
  }
  const float su_c = su_buf[b*KS + c];
  const float cb_c = cb_buf[b*KS + c];

  float4v Pacc[16];
  #pragma unroll
  for (int t = 0; t < 16; ++t) Pacc[t] = (float4v){0.f,0.f,0.f,0.f};
  float S_acc = 0.f, R_acc = 0.f;

  unsigned int* myxl = xl[w];
  const int rbase = 8*(c>>2) + (c&3);

  for (int pass = 0; pass < 4; ++pass) {
    const int n0 = blk*(NTOK/NBLK) + pass*128 + w*32;
    float4v Ct[2];
    float m_t[2], rs_t[2];

    #pragma unroll
    for (int tp = 0; tp < 2; ++tp) {
      const int nloc = rbase + 4*tp;
      const size_t row = (size_t)b*NTOK + (size_t)(n0 + nloc);
      float4v Cacc = (float4v){0.f,0.f,0.f,0.f};
      if constexpr (MODE == 0) {
        const float* fr = feat + row*FEATN;
        unsigned short* xw = xb + row*FEATN;
        float sum = 0.f, sq = 0.f;
        #pragma unroll
        for (int kk = 0; kk < 8; ++kk) {
          const float4v x0 = *reinterpret_cast<const float4v*>(fr + 32*kk + 8*g);
          const float4v x1 = *reinterpret_cast<const float4v*>(fr + 32*kk + 8*g + 4);
          sum += x0[0]+x0[1]+x0[2]+x0[3] + x1[0]+x1[1]+x1[2]+x1[3];
          sq  += x0[0]*x0[0]+x0[1]*x0[1]+x0[2]*x0[2]+x0[3]*x0[3]
               + x1[0]*x1[0]+x1[1]*x1[1]+x1[2]*x1[2]+x1[3]*x1[3];
          bf16x8 af;
          af[0]=(__bf16)x0[0]; af[1]=(__bf16)x0[1]; af[2]=(__bf16)x0[2]; af[3]=(__bf16)x0[3];
          af[4]=(__bf16)x1[0]; af[5]=(__bf16)x1[1]; af[6]=(__bf16)x1[2]; af[7]=(__bf16)x1[3];
          *reinterpret_cast<bf16x8*>(xw + 32*kk + 8*g) = af;
          const uint4v ad = __builtin_bit_cast(uint4v, af);
          const int pb = (16*kk + 4*g)*36 + nloc;
          myxl[pb      ] = ad[0];
          myxl[pb + 36 ] = ad[1];
          myxl[pb + 72 ] = ad[2];
          myxl[pb + 108] = ad[3];
          Cacc = __builtin_amdgcn_mfma_f32_16x16x32_bf16(af, ufrag[kk], Cacc, 0, 0, 0);
        }
        sum += __shfl_xor(sum,16); sum += __shfl_xor(sum,32);
        sq  += __shfl_xor(sq ,16); sq  += __shfl_xor(sq ,32);
        const float mean = sum * (1.f/FEATN);
        const float var  = sq  * (1.f/FEATN) - mean*mean;
        m_t[tp]  = mean;
        rs_t[tp] = rsqrtf(var + LN_EPS);
        float2 st; st.x = m_t[tp]; st.y = rs_t[tp];
        *reinterpret_cast<float2*>(stats + row*2) = st;
      } else {
        const unsigned short* xr = xb + row*FEATN;
        const float2 st = *reinterpret_cast<const float2*>(stats + row*2);
        m_t[tp] = st.x; rs_t[tp] = st.y;
        #pragma unroll
        for (int kk = 0; kk < 8; ++kk) {
          const bf16x8 af = *reinterpret_cast<const bf16x8*>(xr + 32*kk + 8*g);
          const uint4v ad = __builtin_bit_cast(uint4v, af);
          const int pb = (16*kk + 4*g)*36 + nloc;
          myxl[pb      ] = ad[0];
          myxl[pb + 36 ] = ad[1];
          myxl[pb + 72 ] = ad[2];
          myxl[pb + 108] = ad[3];
          Cacc = __builtin_amdgcn_mfma_f32_16x16x32_bf16(af, ufrag[kk], Cacc, 0, 0, 0);
        }
      }
      Ct[tp] = Cacc;
    }

    float arr[8];
    #pragma unroll
    for (int tp = 0; tp < 2; ++tp) {
      float lv[4], rsr[4], mr[4];
      #pragma unroll
      for (int r = 0; r < 4; ++r) {
        const int src = 4*g + r;
        rsr[r] = __shfl(rs_t[tp], src);
        mr[r]  = __shfl(m_t[tp],  src);
        lv[r]  = 0.0625f * (rsr[r]*(Ct[tp][r] - mr[r]*su_c) + cb_c);
      }
      float a_[4];
      #pragma unroll
      for (int r = 0; r < 4; ++r) {
        float v = lv[r];
        v = fmaxf(v, __shfl_xor(v,1));
        v = fmaxf(v, __shfl_xor(v,2));
        v = fmaxf(v, __shfl_xor(v,4));
        v = fmaxf(v, __shfl_xor(v,8));
        const float e = __expf(lv[r] - v);
        float s = e;
        s += __shfl_xor(s,1);
        s += __shfl_xor(s,2);
        s += __shfl_xor(s,4);
        s += __shfl_xor(s,8);
        const float a = e / s;
        a_[r] = a;
        S_acc += a;
        R_acc += a * rsr[r] * mr[r];
        arr[4*tp + r] = a * rsr[r];
      }
      if (last) {
        float4v av = {a_[0], a_[1], a_[2], a_[3]};
        *reinterpret_cast<float4v*>(attn_out + (size_t)(b*KS + c)*NTOK + (size_t)(n0 + 8*g + 4*tp)) = av;
      }
    }
    bf16x8 afrag;
    #pragma unroll
    for (int j = 0; j < 8; ++j) afrag[j] = (__bf16)arr[j];

    #pragma unroll
    for (int t = 0; t < 16; ++t) {
      const unsigned int* rp = &myxl[(t*8 + (c>>1))*36 + 8*g];
      const uint4v q0 = *reinterpret_cast<const uint4v*>(rp);
      const uint4v q1 = *reinterpret_cast<const uint4v*>(rp + 4);
      const unsigned int sel = (c & 1) ? 0x07060302u : 0x05040100u;
      uint4v bd;
      bd[0] = __builtin_amdgcn_perm(q0[1], q0[0], sel);
      bd[1] = __builtin_amdgcn_perm(q0[3], q0[2], sel);
      bd[2] = __builtin_amdgcn_perm(q1[1], q1[0], sel);
      bd[3] = __builtin_amdgcn_perm(q1[3], q1[2], sel);
      const bf16x8 bfrag = __builtin_bit_cast(bf16x8, bd);
      Pacc[t] = __builtin_amdgcn_mfma_f32_16x16x32_bf16(afrag, bfrag, Pacc[t], 0, 0, 0);
    }
  }

  S_acc += __shfl_xor(S_acc,16); S_acc += __shfl_xor(S_acc,32);
  R_acc += __shfl_xor(R_acc,16); R_acc += __shfl_xor(R_acc,32);
  if (g == 0) { ssh[w][c] = S_acc; rsh[w][c] = R_acc; }

  float* pf = reinterpret_cast<float*>(xl[w]);
  #pragma unroll
  for (int t = 0; t < 16; ++t) {
    #pragma unroll
    for (int r = 0; r < 4; ++r) pf[(4*g + r)*256 + t*16 + c] = Pacc[t][r];
  }
  __syncthreads();
  {
    float* outp = P_part + (size_t)blockIdx.x * (KS*DD);
    const float* p0 = reinterpret_cast<const float*>(xl[0]);
    const float* p1 = reinterpret_cast<const float*>(xl[1]);
    const float* p2 = reinterpret_cast<const float*>(xl[2]);
    const float* p3 = reinterpret_cast<const float*>(xl[3]);
    for (int i = tid; i < KS*DD; i += 256) outp[i] = p0[i]+p1[i]+p2[i]+p3[i];
    if (tid < KS) {
      S_part[blockIdx.x*KS + tid] = ssh[0][tid]+ssh[1][tid]+ssh[2][tid]+ssh[3][tid];
      R_part[blockIdx.x*KS + tid] = rsh[0][tid]+rsh[1][tid]+rsh[2][tid]+rsh[3][tid];
    }
  }
}

// ---------------------------------------------------------------- shared tail: LN(g_s,b_s)->q->u/su/cb
__device__ __forceinline__ void lnqu_tail(
    float (&Vs)[4][DD], float (&Ys)[DD][4], float (&Qs)[DD][4],
    float (&Pp)[4][4][DD], float (&SUb)[4][DD], float (&CBb)[4][DD],
    const float* __restrict__ g_s, const float* __restrict__ b_s,
    const unsigned short* __restrict__ Wq_t, const unsigned short* __restrict__ Wk_b,
    const float* __restrict__ g_f, const float* __restrict__ b_f,
    unsigned short* __restrict__ u_buf, float* __restrict__ su_buf, float* __restrict__ cb_buf,
    int b, int k0, int tid)
{
  const int w = tid >> 6, L = tid & 63;
  {
    const float v0 = Vs[w][L], v1 = Vs[w][64+L], v2 = Vs[w][128+L], v3 = Vs[w][192+L];
    float s = v0+v1+v2+v3;
    #pragma unroll
    for (int m = 1; m < 64; m <<= 1) s += __shfl_xor(s, m);
    const float mean = s * (1.f/DD);
    const float d0 = v0-mean, d1 = v1-mean, d2 = v2-mean, d3 = v3-mean;
    float s2 = d0*d0 + d1*d1 + d2*d2 + d3*d3;
    #pragma unroll
    for (int m = 1; m < 64; m <<= 1) s2 += __shfl_xor(s2, m);
    const float rs = rsqrtf(s2 * (1.f/DD) + LN_EPS);
    Ys[L][w]      = d0*rs*g_s[L]      + b_s[L];
    Ys[64+L][w]   = d1*rs*g_s[64+L]   + b_s[64+L];
    Ys[128+L][w]  = d2*rs*g_s[128+L]  + b_s[128+L];
    Ys[192+L][w]  = d3*rs*g_s[192+L]  + b_s[192+L];
  }
  __syncthreads();
  {
    float acc[4][4] = {};
    for (int cc = w*64; cc < w*64+64; ++cc) {
      const float4v xv = *reinterpret_cast<const float4v*>(&Ys[cc][0]);
      const uint2v wr = *reinterpret_cast<const uint2v*>(Wq_t + (size_t)cc*DD + 4*L);
      const float w0 = bflo(wr[0]), w1 = bfhi(wr[0]), w2 = bflo(wr[1]), w3 = bfhi(wr[1]);
      #pragma unroll
      for (int s = 0; s < 4; ++s) {
        acc[s][0] += xv[s]*w0; acc[s][1] += xv[s]*w1;
        acc[s][2] += xv[s]*w2; acc[s][3] += xv[s]*w3;
      }
    }
    #pragma unroll
    for (int s = 0; s < 4; ++s)
      *reinterpret_cast<float4v*>(&Pp[w][s][4*L]) = *reinterpret_cast<const float4v*>(acc[s]);
  }
  __syncthreads();
  for (int i = tid; i < 4*DD; i += 256) {
    const int kk = i >> 8, d = i & 255;
    Qs[d][kk] = Pp[0][kk][d] + Pp[1][kk][d] + Pp[2][kk][d] + Pp[3][kk][d];
  }
  __syncthreads();
  {
    float acc[4][4] = {};
    for (int d = w*64; d < w*64+64; ++d) {
      const float4v xv = *reinterpret_cast<const float4v*>(&Qs[d][0]);
      const uint2v wr = *reinterpret_cast<const uint2v*>(Wk_b + (size_t)d*DD + 4*L);
      const float w0 = bflo(wr[0]), w1 = bfhi(wr[0]), w2 = bflo(wr[1]), w3 = bfhi(wr[1]);
      #pragma unroll
      for (int s = 0; s < 4; ++s) {
        acc[s][0] += xv[s]*w0; acc[s][1] += xv[s]*w1;
        acc[s][2] += xv[s]*w2; acc[s][3] += xv[s]*w3;
      }
    }
    #pragma unroll
    for (int s = 0; s < 4; ++s)
      *reinterpret_cast<float4v*>(&Pp[w][s][4*L]) = *reinterpret_cast<const float4v*>(acc[s]);
  }
  __syncthreads();
  for (int i = tid; i < 4*DD; i += 256) {
    const int kk = i >> 8, cc = i & 255;
    const float qk = Pp[0][kk][cc] + Pp[1][kk][cc] + Pp[2][kk][cc] + Pp[3][kk][cc];
    const float uv = qk * g_f[cc];
    u_buf[(size_t)(b*KS + k0 + kk)*DD + cc] = f2bf(uv);
    SUb[kk][cc] = uv;
    CBb[kk][cc] = qk * b_f[cc];
  }
  __syncthreads();
  {
    float s  = SUb[w][L] + SUb[w][64+L] + SUb[w][128+L] + SUb[w][192+L];
    float cv = CBb[w][L] + CBb[w][64+L] + CBb[w][128+L] + CBb[w][192+L];
    #pragma unroll
    for (int m = 1; m < 64; m <<= 1) { s += __shfl_xor(s, m); cv += __shfl_xor(cv, m); }
    if (L == 0) { su_buf[b*KS + k0 + w] = s; cb_buf[b*KS + k0 + w] = cv; }
  }
}

// ---------------------------------------------------------------- K0: initial u from slots_init
__global__ void k0_kernel(const float* __restrict__ slots_init,
                          const float* __restrict__ g_s, const float* __restrict__ b_s,
                          const unsigned short* __restrict__ Wq_t, const unsigned short* __restrict__ Wk_b,
                          const float* __restrict__ g_f, const float* __restrict__ b_f,
                          unsigned short* __restrict__ u_buf, float* __restrict__ su_buf,
                          float* __restrict__ cb_buf)
{
  const int b = blockIdx.x >> 2, k0 = (blockIdx.x & 3) * 4;
  const int tid = threadIdx.x;
  __shared__ float Vs[4][DD];
  __shared__ float Ys[DD][4];
  __shared__ float Qs[DD][4];
  __shared__ float Pp[4][4][DD];
  __shared__ float SUb[4][DD];
  __shared__ float CBb[4][DD];
  for (int i = tid; i < 4*DD; i += 256) {
    const int kk = i >> 8, d = i & 255;
    Vs[kk][d] = slots_init[(size_t)(b*KS + k0 + kk)*DD + d];
  }
  __syncthreads();
  lnqu_tail(Vs, Ys, Qs, Pp, SUb, CBb, g_s, b_s, Wq_t, Wk_b, g_f, b_f,
            u_buf, su_buf, cb_buf, b, k0, tid);
}

// ---------------------------------------------------------------- K2: reduce+Wv+GRU+LN
__global__ void k2_kernel(const float* __restrict__ P_part, const float* __restrict__ S_part,
                          const float* __restrict__ R_part, const float* __restrict__ slots_in,
                          const float* __restrict__ g_f, const float* __restrict__ b_f,
                          const unsigned short* __restrict__ Wv_t,
                          const unsigned short* __restrict__ wih_t,
                          const unsigned short* __restrict__ whh_t,
                          const float* __restrict__ b_ih, const float* __restrict__ b_hh,
                          const float* __restrict__ g_m, const float* __restrict__ b_m,
                          float* __restrict__ hprime, float* __restrict__ y2)
{
  const int b = blockIdx.x >> 2, k0 = (blockIdx.x & 3) * 4;
  const int tid = threadIdx.x;
  const int w = tid >> 6, L = tid & 63;
  __shared__ float Xs[DD][4];
  __shared__ float Xs2[DD][4];
  __shared__ float Xs3[DD][4];
  __shared__ float Pp[4][4][DD];
  __shared__ float Gi[4][768];
  __shared__ float Gh[4][768];
  __shared__ float Hp[4][DD];
  __shared__ float SR[2][4];

  for (int i = tid; i < 4*DD; i += 256) {
    const int kk = i >> 8, cc = i & 255;
    Xs3[cc][kk] = slots_in[(size_t)(b*KS + k0 + kk)*DD + cc];
  }
  if (tid < 8) {
    const int kk = tid & 3;
    const float* src = (tid < 4) ? S_part : R_part;
    float s = 0.f;
    for (int p = 0; p < NBLK; ++p) s += src[(b*NBLK + p)*KS + k0 + kk];
    SR[tid >> 2][kk] = s;
  }
  __syncthreads();
  for (int i = tid; i < 4*DD; i += 256) {
    const int kk = i >> 8, cc = i & 255;
    float P = 0.f;
    for (int p = 0; p < NBLK; ++p)
      P += P_part[(size_t)((b*NBLK + p)*KS + k0 + kk)*DD + cc];
    const float S = SR[0][kk], R = SR[1][kk];
    Xs[cc][kk] = (g_f[cc]*(P - R) + S*b_f[cc]) / (S + 1.0f);
  }
  __syncthreads();

  // upd = T @ Wv^T : cols 256, K-split across waves
  {
    float acc[4][4] = {};
    for (int cc = w*64; cc < w*64+64; ++cc) {
      const float4v xv = *reinterpret_cast<const float4v*>(&Xs[cc][0]);
      const uint2v wr = *reinterpret_cast<const uint2v*>(Wv_t + (size_t)cc*DD + 4*L);
      const float w0 = bflo(wr[0]), w1 = bfhi(wr[0]), w2 = bflo(wr[1]), w3 = bfhi(wr[1]);
      #pragma unroll
      for (int s = 0; s < 4; ++s) {
        acc[s][0] += xv[s]*w0; acc[s][1] += xv[s]*w1;
        acc[s][2] += xv[s]*w2; acc[s][3] += xv[s]*w3;
      }
    }
    #pragma unroll
    for (int s = 0; s < 4; ++s)
      *reinterpret_cast<float4v*>(&Pp[w][s][4*L]) = *reinterpret_cast<const float4v*>(acc[s]);
  }
  __syncthreads();
  for (int i = tid; i < 4*DD; i += 256) {
    const int kk = i >> 8, cc = i & 255;
    Xs2[cc][kk] = Pp[0][kk][cc] + Pp[1][kk][cc] + Pp[2][kk][cc] + Pp[3][kk][cc];
  }
  __syncthreads();

  // gi = upd @ w_ih^T + b_ih ; gh = slots @ w_hh^T + b_hh   (cols 768, 3 waves)
  if (tid < 192) {
    const int j0 = tid * 4;
    float gia[4][4], gha[4][4];
    const float4v bi = *reinterpret_cast<const float4v*>(b_ih + j0);
    const float4v bh = *reinterpret_cast<const float4v*>(b_hh + j0);
    #pragma unroll
    for (int s = 0; s < 4; ++s)
      #pragma unroll
      for (int j = 0; j < 4; ++j) { gia[s][j] = bi[j]; gha[s][j] = bh[j]; }
    for (int cc = 0; cc < DD; ++cc) {
      const float4v xi = *reinterpret_cast<const float4v*>(&Xs2[cc][0]);
      const float4v xh = *reinterpret_cast<const float4v*>(&Xs3[cc][0]);
      const uint2v wi = *reinterpret_cast<const uint2v*>(wih_t + (size_t)cc*768 + j0);
      const uint2v wh = *reinterpret_cast<const uint2v*>(whh_t + (size_t)cc*768 + j0);
      const float wi0 = bflo(wi[0]), wi1 = bfhi(wi[0]), wi2 = bflo(wi[1]), wi3 = bfhi(wi[1]);
      const float wh0 = bflo(wh[0]), wh1 = bfhi(wh[0]), wh2 = bflo(wh[1]), wh3 = bfhi(wh[1]);
      #pragma unroll
      for (int s = 0; s < 4; ++s) {
        gia[s][0] += xi[s]*wi0; gia[s][1] += xi[s]*wi1; gia[s][2] += xi[s]*wi2; gia[s][3] += xi[s]*wi3;
        gha[s][0] += xh[s]*wh0; gha[s][1] += xh[s]*wh1; gha[s][2] += xh[s]*wh2; gha[s][3] += xh[s]*wh3;
      }
    }
    #pragma unroll
    for (int s = 0; s < 4; ++s) {
      *reinterpret_cast<float4v*>(&Gi[s][j0]) = *reinterpret_cast<const float4v*>(gia[s]);
      *reinterpret_cast<float4v*>(&Gh[s][j0]) = *reinterpret_cast<const float4v*>(gha[s]);
    }
  }
  __syncthreads();
  for (int i = tid; i < 4*DD; i += 256) {
    const int kk = i >> 8, d = i & 255;
    const float r = 1.f/(1.f + __expf(-(Gi[kk][d] + Gh[kk][d])));
    const float z = 1.f/(1.f + __expf(-(Gi[kk][DD + d] + Gh[kk][DD + d])));
    const float n = tanhf(Gi[kk][2*DD + d] + r*Gh[kk][2*DD + d]);
    const float h = Xs3[d][kk];
    const float hp = (1.f - z)*n + z*h;
    Hp[kk][d] = hp;
    hprime[(size_t)(b*KS + k0 + kk)*DD + d] = hp;
  }
  __syncthreads();
  {
    const float v0 = Hp[w][L], v1 = Hp[w][64+L], v2 = Hp[w][128+L], v3 = Hp[w][192+L];
    float s = v0+v1+v2+v3;
    #pragma unroll
    for (int m = 1; m < 64; m <<= 1) s += __shfl_xor(s, m);
    const float mean = s * (1.f/DD);
    const float d0 = v0-mean, d1 = v1-mean, d2 = v2-mean, d3 = v3-mean;
    float s2 = d0*d0 + d1*d1 + d2*d2 + d3*d3;
    #pragma unroll
    for (int m = 1; m < 64; m <<= 1) s2 += __shfl_xor(s2, m);
    const float rs = rsqrtf(s2 * (1.f/DD) + LN_EPS);
    float* yo = y2 + (size_t)(b*KS + k0 + w)*DD;
    yo[L]     = d0*rs*g_m[L]     + b_m[L];
    yo[64+L]  = d1*rs*g_m[64+L]  + b_m[64+L];
    yo[128+L] = d2*rs*g_m[128+L] + b_m[128+L];
    yo[192+L] = d3*rs*g_m[192+L] + b_m[192+L];
  }
}

// ---------------------------------------------------------------- K3: MLP + residual (+ next LN/q/u)
__global__ void k3_kernel(const float* __restrict__ y2,
                          const unsigned short* __restrict__ W1_t, const float* __restrict__ b1,
                          const unsigned short* __restrict__ W2_t, const float* __restrict__ b2,
                          const float* __restrict__ hprime,
                          const float* __restrict__ g_s, const float* __restrict__ b_s,
                          const unsigned short* __restrict__ Wq_t, const unsigned short* __restrict__ Wk_b,
                          const float* __restrict__ g_f, const float* __restrict__ b_f,
                          float* __restrict__ slots_next, float* __restrict__ out_slots, int last,
                          unsigned short* __restrict__ u_buf, float* __restrict__ su_buf,
                          float* __restrict__ cb_buf)
{
  const int b = blockIdx.x >> 2, k0 = (blockIdx.x & 3) * 4;
  const int tid = threadIdx.x;
  const int w = tid >> 6, L = tid & 63;
  __shared__ float Xs[DD][4];
  __shared__ float Hs[1024][4];
  __shared__ float Pp[4][4][DD];
  __shared__ float Vs[4][DD];
  __shared__ float Ys[DD][4];
  __shared__ float Qs[DD][4];
  __shared__ float SUb[4][DD];
  __shared__ float CBb[4][DD];

  for (int i = tid; i < 4*DD; i += 256) {
    const int kk = i >> 8, cc = i & 255;
    Xs[cc][kk] = y2[(size_t)(b*KS + k0 + kk)*DD + cc];
  }
  __syncthreads();
  // hid = relu(y2 @ W1^T + b1): cols 1024, all threads
  {
    const int j0 = tid * 4;
    float acc[4][4];
    const float4v bb = *reinterpret_cast<const float4v*>(b1 + j0);
    #pragma unroll
    for (int s = 0; s < 4; ++s)
      #pragma unroll
      for (int j = 0; j < 4; ++j) acc[s][j] = bb[j];
    for (int cc = 0; cc < DD; ++cc) {
      const float4v xv = *reinterpret_cast<const float4v*>(&Xs[cc][0]);
      const uint2v wr = *reinterpret_cast<const uint2v*>(W1_t + (size_t)cc*1024 + j0);
      const float w0 = bflo(wr[0]), w1 = bfhi(wr[0]), w2 = bflo(wr[1]), w3 = bfhi(wr[1]);
      #pragma unroll
      for (int s = 0; s < 4; ++s) {
        acc[s][0] += xv[s]*w0; acc[s][1] += xv[s]*w1;
        acc[s][2] += xv[s]*w2; acc[s][3] += xv[s]*w3;
      }
    }
    float* tmp = &Pp[0][0][0];
    #pragma unroll
    for (int s = 0; s < 4; ++s) {
      float4v rv;
      #pragma unroll
      for (int j = 0; j < 4; ++j) rv[j] = fmaxf(acc[s][j], 0.f);
      *reinterpret_cast<float4v*>(&tmp[s*1024 + j0]) = rv;
    }
  }
  __syncthreads();
  {
    const float* tmp = &Pp[0][0][0];
    for (int i = tid; i < 4096; i += 256) {
      const int j = i & 1023, s = i >> 10;
      Hs[j][s] = tmp[s*1024 + j];
    }
  }
  __syncthreads();
  // o = hid @ W2^T + b2: cols 256, Kin 1024 K-split
  {
    float acc[4][4] = {};
    for (int cc = w*256; cc < w*256+256; ++cc) {
      const float4v xv = *reinterpret_cast<const float4v*>(&Hs[cc][0]);
      const uint2v wr = *reinterpret_cast<const uint2v*>(W2_t + (size_t)cc*DD + 4*L);
      const float w0 = bflo(wr[0]), w1 = bfhi(wr[0]), w2 = bflo(wr[1]), w3 = bfhi(wr[1]);
      #pragma unroll
      for (int s = 0; s < 4; ++s) {
        acc[s][0] += xv[s]*w0; acc[s][1] += xv[s]*w1;
        acc[s][2] += xv[s]*w2; acc[s][3] += xv[s]*w3;
      }
    }
    #pragma unroll
    for (int s = 0; s < 4; ++s)
      *reinterpret_cast<float4v*>(&Pp[w][s][4*L]) = *reinterpret_cast<const float4v*>(acc[s]);
  }
  __syncthreads();
  for (int i = tid; i < 4*DD; i += 256) {
    const int kk = i >> 8, d = i & 255;
    const float v = Pp[0][kk][d] + Pp[1][kk][d] + Pp[2][kk][d] + Pp[3][kk][d]
                  + b2[d] + hprime[(size_t)(b*KS + k0 + kk)*DD + d];
    Vs[kk][d] = v;
    slots_next[(size_t)(b*KS + k0 + kk)*DD + d] = v;
    if (last) out_slots[(size_t)(b*KS + k0 + kk)*DD + d] = v;
  }
  __syncthreads();
  if (!last)
    lnqu_tail(Vs, Ys, Qs, Pp, SUb, CBb, g_s, b_s, Wq_t, Wk_b, g_f, b_f,
              u_buf, su_buf, cb_buf, b, k0, tid);
}

// ---------------------------------------------------------------- host
extern "C" void kernel_launch(void* const* d_in, const int* in_sizes, int n_in,
                              void* d_out, int out_size, void* d_ws, size_t ws_size,
                              hipStream_t stream)
{
  const float* features   = (const float*)d_in[0];
  const float* slots_init = (const float*)d_in[1];
  const float* g_f = (const float*)d_in[2];
  const float* b_f = (const float*)d_in[3];
  const float* g_s = (const float*)d_in[4];
  const float* b_s = (const float*)d_in[5];
  const float* g_m = (const float*)d_in[6];
  const float* b_m = (const float*)d_in[7];
  const float* Wq  = (const float*)d_in[8];
  const float* Wk  = (const float*)d_in[9];
  const float* Wv  = (const float*)d_in[10];
  const float* w_ih = (const float*)d_in[11];
  const float* w_hh = (const float*)d_in[12];
  const float* b_ih = (const float*)d_in[13];
  const float* b_hh = (const float*)d_in[14];
  const float* W1  = (const float*)d_in[15];
  const float* b1  = (const float*)d_in[16];
  const float* W2  = (const float*)d_in[17];
  const float* b2  = (const float*)d_in[18];

  float* out_slots = (float*)d_out;
  float* out_attn  = out_slots + (size_t)BB*KS*DD;

  char* ws = (char*)d_ws;
  size_t off = 0;
  auto alloc = [&](size_t bytes) -> void* {
    void* p = ws + off;
    off += (bytes + 255) & ~(size_t)255;
    return p;
  };
  unsigned short* u_buf  = (unsigned short*)alloc((size_t)BB*KS*DD*2);
  float*          su_buf = (float*)alloc((size_t)BB*KS*4);
  float*          cb_buf = (float*)alloc((size_t)BB*KS*4);
  float*          P_part = (float*)alloc((size_t)BB*NBLK*KS*DD*4);
  float*          S_part = (float*)alloc((size_t)BB*NBLK*KS*4);
  float*          R_part = (float*)alloc((size_t)BB*NBLK*KS*4);
  float*          slots_ws = (float*)alloc((size_t)BB*KS*DD*4);
  float*          hprime = (float*)alloc((size_t)BB*KS*DD*4);
  float*          y2     = (float*)alloc((size_t)BB*KS*DD*4);
  unsigned short* Wv_t  = (unsigned short*)alloc((size_t)256*256*2);
  unsigned short* wih_t = (unsigned short*)alloc((size_t)256*768*2);
  unsigned short* whh_t = (unsigned short*)alloc((size_t)256*768*2);
  unsigned short* W1_t  = (unsigned short*)alloc((size_t)256*1024*2);
  unsigned short* W2_t  = (unsigned short*)alloc((size_t)1024*256*2);
  unsigned short* Wq_t  = (unsigned short*)alloc((size_t)256*256*2);
  unsigned short* Wk_b  = (unsigned short*)alloc((size_t)256*256*2);
  float*          stats = (float*)alloc((size_t)BB*NTOK*2*4);
  unsigned short* xb    = (unsigned short*)alloc((size_t)BB*NTOK*FEATN*2);
  (void)in_sizes; (void)n_in; (void)out_size; (void)ws_size;

  prep_w_kernel<<<272, 256, 0, stream>>>(Wv, w_ih, w_hh, W1, W2, Wq, Wk,
                                         Wv_t, wih_t, whh_t, W1_t, W2_t, Wq_t, Wk_b);
  k0_kernel<<<BB*4, 256, 0, stream>>>(slots_init, g_s, b_s, Wq_t, Wk_b, g_f, b_f,
                                      u_buf, su_buf, cb_buf);

  for (int it = 0; it < 3; ++it) {
    const int last = (it == 2);
    if (it == 0)
      big_attn_kernel<0><<<BB*NBLK, 256, 0, stream>>>(features, xb, stats, u_buf, su_buf, cb_buf,
                                                      P_part, S_part, R_part, out_attn, last);
    else
      big_attn_kernel<1><<<BB*NBLK, 256, 0, stream>>>(features, xb, stats, u_buf, su_buf, cb_buf,
                                                      P_part, S_part, R_part, out_attn, last);
    const float* slots_in = (it == 0) ? slots_init : slots_ws;
    k2_kernel<<<BB*4, 256, 0, stream>>>(P_part, S_part, R_part, slots_in, g_f, b_f,
                                        Wv_t, wih_t, whh_t, b_ih, b_hh, g_m, b_m,
                                        hprime, y2);
    k3_kernel<<<BB*4, 256, 0, stream>>>(y2, W1_t, b1, W2_t, b2, hprime, g_s, b_s,
                                        Wq_t, Wk_b, g_f, b_f,
                                        slots_ws, out_slots, last,
                                        u_buf, su_buf, cb_buf);
  }
}

// Round 3
// 654.719 us; speedup vs baseline: 1.0341x; 1.0341x over previous
//
// SlotAttention fused forward for MI355X (gfx950) — round 3.
// One kernel per iteration: phase A (big attention pass, 512 blocks) + flag
// handshake + phase B (64 blocks: P/S/R reduce, Wv, GRU, LN, MLP, residual,
// next-iteration LN->q->u) reusing the 73.7KB LDS arena. 5 dispatches total.
// Flags: 4 private copies (one per waiter block), tag=it+1, reset after use.
#include <hip/hip_runtime.h>
#include <cstdint>
#include <cstddef>

#define BB    16
#define NTOK  16384
#define KS    16
#define DD    256
#define FEATN 256
#define NBLK  32
#define LN_EPS 1e-5f

typedef float        float4v __attribute__((ext_vector_type(4)));
typedef unsigned int uint4v  __attribute__((ext_vector_type(4)));
typedef unsigned int uint2v  __attribute__((ext_vector_type(2)));
typedef __bf16       bf16x8  __attribute__((ext_vector_type(8)));

__device__ __forceinline__ float bflo(unsigned u){ return __builtin_bit_cast(float, u << 16); }
__device__ __forceinline__ float bfhi(unsigned u){ return __builtin_bit_cast(float, u & 0xffff0000u); }
__device__ __forceinline__ unsigned short f2bf(float v){ __bf16 b = (__bf16)v; return __builtin_bit_cast(unsigned short, b); }

// ---------------------------------------------------------------- weight prep
__global__ void prep_w_kernel(const float* __restrict__ Wv, const float* __restrict__ w_ih,
                              const float* __restrict__ w_hh, const float* __restrict__ W1,
                              const float* __restrict__ W2, const float* __restrict__ Wq,
                              const float* __restrict__ Wk,
                              unsigned short* __restrict__ Wv_t, unsigned short* __restrict__ wih_t,
                              unsigned short* __restrict__ whh_t, unsigned short* __restrict__ W1_t,
                              unsigned short* __restrict__ W2_t, unsigned short* __restrict__ Wq_t,
                              unsigned short* __restrict__ Wk_b)
{
  __shared__ float tile[64][65];
  const int t = blockIdx.x, tid = threadIdx.x;
  const float* src; unsigned short* dst; int R, C, base;
  if      (t < 16)  { src = Wv;   dst = Wv_t;  R = 256;  C = 256;  base = 0;   }
  else if (t < 64)  { src = w_ih; dst = wih_t; R = 768;  C = 256;  base = 16;  }
  else if (t < 112) { src = w_hh; dst = whh_t; R = 768;  C = 256;  base = 64;  }
  else if (t < 176) { src = W1;   dst = W1_t;  R = 1024; C = 256;  base = 112; }
  else if (t < 240) { src = W2;   dst = W2_t;  R = 256;  C = 1024; base = 176; }
  else if (t < 256) { src = Wq;   dst = Wq_t;  R = 256;  C = 256;  base = 240; }
  else {
    const int t2 = t - 256;
    for (int i = tid; i < 4096; i += 256) {
      const int idx = t2*4096 + i;
      Wk_b[idx] = f2bf(Wk[idx]);
    }
    return;
  }
  const int tt = t - base;
  const int tiles_r = R >> 6;
  const int r0 = (tt % tiles_r) * 64, c0 = (tt / tiles_r) * 64;
  const int j = tid & 63, i0 = (tid >> 6) * 16;
  for (int s = 0; s < 16; ++s)
    tile[i0 + s][j] = src[(size_t)(r0 + i0 + s)*C + c0 + j];
  __syncthreads();
  for (int s = 0; s < 16; ++s) {
    const int i = i0 + s;
    dst[(size_t)(c0 + i)*R + r0 + j] = f2bf(tile[j][i]);
  }
}

// ---------------------------------------------------------------- LN->q->u/su/cb tail (pointer form)
// Vs: [4][256] row-major; Ys/Qs: [256][4]; Pp: [4][4][256]; SUb/CBb: [4][256]
__device__ __forceinline__ void lnqu_tail_p(
    const float* Vs, float* Ys, float* Qs, float* Pp, float* SUb, float* CBb,
    const float* __restrict__ g_s, const float* __restrict__ b_s,
    const unsigned short* __restrict__ Wq_t, const unsigned short* __restrict__ Wk_b,
    const float* __restrict__ g_f, const float* __restrict__ b_f,
    unsigned short* __restrict__ u_buf, float* __restrict__ su_buf, float* __restrict__ cb_buf,
    int b, int k0, int tid)
{
  const int w = tid >> 6, L = tid & 63;
  {
    const float v0 = Vs[w*256+L], v1 = Vs[w*256+64+L], v2 = Vs[w*256+128+L], v3 = Vs[w*256+192+L];
    float s = v0+v1+v2+v3;
    #pragma unroll
    for (int m = 1; m < 64; m <<= 1) s += __shfl_xor(s, m);
    const float mean = s * (1.f/DD);
    const float d0 = v0-mean, d1 = v1-mean, d2 = v2-mean, d3 = v3-mean;
    float s2 = d0*d0 + d1*d1 + d2*d2 + d3*d3;
    #pragma unroll
    for (int m = 1; m < 64; m <<= 1) s2 += __shfl_xor(s2, m);
    const float rs = rsqrtf(s2 * (1.f/DD) + LN_EPS);
    Ys[L*4+w]       = d0*rs*g_s[L]      + b_s[L];
    Ys[(64+L)*4+w]  = d1*rs*g_s[64+L]   + b_s[64+L];
    Ys[(128+L)*4+w] = d2*rs*g_s[128+L]  + b_s[128+L];
    Ys[(192+L)*4+w] = d3*rs*g_s[192+L]  + b_s[192+L];
  }
  __syncthreads();
  {
    float acc[4][4] = {};
    for (int cc = w*64; cc < w*64+64; ++cc) {
      const float4v xv = *reinterpret_cast<const float4v*>(Ys + cc*4);
      const uint2v wr = *reinterpret_cast<const uint2v*>(Wq_t + (size_t)cc*DD + 4*L);
      const float w0 = bflo(wr[0]), w1 = bfhi(wr[0]), w2 = bflo(wr[1]), w3 = bfhi(wr[1]);
      #pragma unroll
      for (int s = 0; s < 4; ++s) {
        acc[s][0] += xv[s]*w0; acc[s][1] += xv[s]*w1;
        acc[s][2] += xv[s]*w2; acc[s][3] += xv[s]*w3;
      }
    }
    #pragma unroll
    for (int s = 0; s < 4; ++s)
      *reinterpret_cast<float4v*>(Pp + (w*4+s)*256 + 4*L) = *reinterpret_cast<const float4v*>(acc[s]);
  }
  __syncthreads();
  for (int i = tid; i < 4*DD; i += 256) {
    const int kk = i >> 8, d = i & 255;
    Qs[d*4+kk] = Pp[(0*4+kk)*256+d] + Pp[(1*4+kk)*256+d] + Pp[(2*4+kk)*256+d] + Pp[(3*4+kk)*256+d];
  }
  __syncthreads();
  {
    float acc[4][4] = {};
    for (int d = w*64; d < w*64+64; ++d) {
      const float4v xv = *reinterpret_cast<const float4v*>(Qs + d*4);
      const uint2v wr = *reinterpret_cast<const uint2v*>(Wk_b + (size_t)d*DD + 4*L);
      const float w0 = bflo(wr[0]), w1 = bfhi(wr[0]), w2 = bflo(wr[1]), w3 = bfhi(wr[1]);
      #pragma unroll
      for (int s = 0; s < 4; ++s) {
        acc[s][0] += xv[s]*w0; acc[s][1] += xv[s]*w1;
        acc[s][2] += xv[s]*w2; acc[s][3] += xv[s]*w3;
      }
    }
    #pragma unroll
    for (int s = 0; s < 4; ++s)
      *reinterpret_cast<float4v*>(Pp + (w*4+s)*256 + 4*L) = *reinterpret_cast<const float4v*>(acc[s]);
  }
  __syncthreads();
  for (int i = tid; i < 4*DD; i += 256) {
    const int kk = i >> 8, cc = i & 255;
    const float qk = Pp[(0*4+kk)*256+cc] + Pp[(1*4+kk)*256+cc] + Pp[(2*4+kk)*256+cc] + Pp[(3*4+kk)*256+cc];
    const float uv = qk * g_f[cc];
    u_buf[(size_t)(b*KS + k0 + kk)*DD + cc] = f2bf(uv);
    SUb[kk*256+cc] = uv;
    CBb[kk*256+cc] = qk * b_f[cc];
  }
  __syncthreads();
  {
    float s  = SUb[w*256+L] + SUb[w*256+64+L] + SUb[w*256+128+L] + SUb[w*256+192+L];
    float cv = CBb[w*256+L] + CBb[w*256+64+L] + CBb[w*256+128+L] + CBb[w*256+192+L];
    #pragma unroll
    for (int m = 1; m < 64; m <<= 1) { s += __shfl_xor(s, m); cv += __shfl_xor(cv, m); }
    if (L == 0) { su_buf[b*KS + k0 + w] = s; cb_buf[b*KS + k0 + w] = cv; }
  }
}

// ---------------------------------------------------------------- K0: initial u from slots_init
__global__ void k0_kernel(const float* __restrict__ slots_init,
                          const float* __restrict__ g_s, const float* __restrict__ b_s,
                          const unsigned short* __restrict__ Wq_t, const unsigned short* __restrict__ Wk_b,
                          const float* __restrict__ g_f, const float* __restrict__ b_f,
                          unsigned short* __restrict__ u_buf, float* __restrict__ su_buf,
                          float* __restrict__ cb_buf)
{
  const int b = blockIdx.x >> 2, k0 = (blockIdx.x & 3) * 4;
  const int tid = threadIdx.x;
  __shared__ __align__(16) float Vs[4*DD];
  __shared__ __align__(16) float Ys[DD*4];
  __shared__ __align__(16) float Qs[DD*4];
  __shared__ __align__(16) float Pp[4*4*DD];
  __shared__ __align__(16) float SUb[4*DD];
  __shared__ __align__(16) float CBb[4*DD];
  for (int i = tid; i < 4*DD; i += 256)
    Vs[i] = slots_init[(size_t)(b*KS + k0)*DD + i];
  __syncthreads();
  lnqu_tail_p(Vs, Ys, Qs, Pp, SUb, CBb, g_s, b_s, Wq_t, Wk_b, g_f, b_f,
              u_buf, su_buf, cb_buf, b, k0, tid);
}

// ---------------------------------------------------------------- one full iteration
template<int MODE, int LAST>
__launch_bounds__(256, 2)
__global__ void iter_kernel(const float* __restrict__ feat,
                            unsigned short* __restrict__ xb, float* __restrict__ stats,
                            unsigned short* __restrict__ u_buf,
                            float* __restrict__ su_buf, float* __restrict__ cb_buf,
                            float* __restrict__ P_part, float* __restrict__ S_part,
                            float* __restrict__ R_part, float* __restrict__ attn_out,
                            const float* __restrict__ slots_in, float* __restrict__ slots_next,
                            const float* __restrict__ g_f, const float* __restrict__ b_f,
                            const unsigned short* __restrict__ Wv_t,
                            const unsigned short* __restrict__ wih_t,
                            const unsigned short* __restrict__ whh_t,
                            const float* __restrict__ b_ih, const float* __restrict__ b_hh,
                            const float* __restrict__ g_m, const float* __restrict__ b_m,
                            const unsigned short* __restrict__ W1_t, const float* __restrict__ b1,
                            const unsigned short* __restrict__ W2_t, const float* __restrict__ b2v,
                            const float* __restrict__ g_s, const float* __restrict__ b_s,
                            const unsigned short* __restrict__ Wq_t,
                            const unsigned short* __restrict__ Wk_b,
                            float* __restrict__ out_slots, int* __restrict__ flags, int tag)
{
  __shared__ __align__(16) char arena[73728];
  __shared__ float ssh[4][16];
  __shared__ float rsh[4][16];

  const int tid = threadIdx.x;
  const int w = tid >> 6;
  const int l = tid & 63;
  const int c = l & 15;
  const int g = l >> 4;

  // ================= PHASE A: streaming attention pass =================
  {
    const int b   = blockIdx.x / NBLK;
    const int blk = blockIdx.x - b*NBLK;

    bf16x8 ufrag[8];
    {
      const bf16x8* up = reinterpret_cast<const bf16x8*>(u_buf + (size_t)(b*KS + c)*DD);
      #pragma unroll
      for (int kk = 0; kk < 8; ++kk) ufrag[kk] = up[4*kk + g];
    }
    const float su_c = su_buf[b*KS + c];
    const float cb_c = cb_buf[b*KS + c];

    float4v Pacc[16];
    #pragma unroll
    for (int t = 0; t < 16; ++t) Pacc[t] = (float4v){0.f,0.f,0.f,0.f};
    float S_acc = 0.f, R_acc = 0.f;

    unsigned int* myxl = reinterpret_cast<unsigned int*>(arena) + w*4608;
    const int rbase = 8*(c>>2) + (c&3);

    for (int pass = 0; pass < 4; ++pass) {
      const int n0 = blk*(NTOK/NBLK) + pass*128 + w*32;
      float4v Ct[2];
      float m_t[2], rs_t[2];

      #pragma unroll
      for (int tp = 0; tp < 2; ++tp) {
        const int nloc = rbase + 4*tp;
        const size_t row = (size_t)b*NTOK + (size_t)(n0 + nloc);
        float4v Cacc = (float4v){0.f,0.f,0.f,0.f};
        if constexpr (MODE == 0) {
          const float* fr = feat + row*FEATN;
          unsigned short* xw = xb + row*FEATN;
          float sum = 0.f, sq = 0.f;
          #pragma unroll
          for (int kk = 0; kk < 8; ++kk) {
            const float4v x0 = *reinterpret_cast<const float4v*>(fr + 32*kk + 8*g);
            const float4v x1 = *reinterpret_cast<const float4v*>(fr + 32*kk + 8*g + 4);
            sum += x0[0]+x0[1]+x0[2]+x0[3] + x1[0]+x1[1]+x1[2]+x1[3];
            sq  += x0[0]*x0[0]+x0[1]*x0[1]+x0[2]*x0[2]+x0[3]*x0[3]
                 + x1[0]*x1[0]+x1[1]*x1[1]+x1[2]*x1[2]+x1[3]*x1[3];
            bf16x8 af;
            af[0]=(__bf16)x0[0]; af[1]=(__bf16)x0[1]; af[2]=(__bf16)x0[2]; af[3]=(__bf16)x0[3];
            af[4]=(__bf16)x1[0]; af[5]=(__bf16)x1[1]; af[6]=(__bf16)x1[2]; af[7]=(__bf16)x1[3];
            *reinterpret_cast<bf16x8*>(xw + 32*kk + 8*g) = af;
            const uint4v ad = __builtin_bit_cast(uint4v, af);
            const int pb = (16*kk + 4*g)*36 + nloc;
            myxl[pb      ] = ad[0];
            myxl[pb + 36 ] = ad[1];
            myxl[pb + 72 ] = ad[2];
            myxl[pb + 108] = ad[3];
            Cacc = __builtin_amdgcn_mfma_f32_16x16x32_bf16(af, ufrag[kk], Cacc, 0, 0, 0);
          }
          sum += __shfl_xor(sum,16); sum += __shfl_xor(sum,32);
          sq  += __shfl_xor(sq ,16); sq  += __shfl_xor(sq ,32);
          const float mean = sum * (1.f/FEATN);
          const float var  = sq  * (1.f/FEATN) - mean*mean;
          m_t[tp]  = mean;
          rs_t[tp] = rsqrtf(var + LN_EPS);
          float2 st; st.x = m_t[tp]; st.y = rs_t[tp];
          *reinterpret_cast<float2*>(stats + row*2) = st;
        } else {
          const unsigned short* xr = xb + row*FEATN;
          const float2 st = *reinterpret_cast<const float2*>(stats + row*2);
          m_t[tp] = st.x; rs_t[tp] = st.y;
          #pragma unroll
          for (int kk = 0; kk < 8; ++kk) {
            const bf16x8 af = *reinterpret_cast<const bf16x8*>(xr + 32*kk + 8*g);
            const uint4v ad = __builtin_bit_cast(uint4v, af);
            const int pb = (16*kk + 4*g)*36 + nloc;
            myxl[pb      ] = ad[0];
            myxl[pb + 36 ] = ad[1];
            myxl[pb + 72 ] = ad[2];
            myxl[pb + 108] = ad[3];
            Cacc = __builtin_amdgcn_mfma_f32_16x16x32_bf16(af, ufrag[kk], Cacc, 0, 0, 0);
          }
        }
        Ct[tp] = Cacc;
      }

      float arr[8];
      #pragma unroll
      for (int tp = 0; tp < 2; ++tp) {
        float lv[4], rsr[4], mr[4];
        #pragma unroll
        for (int r = 0; r < 4; ++r) {
          const int src = 4*g + r;
          rsr[r] = __shfl(rs_t[tp], src);
          mr[r]  = __shfl(m_t[tp],  src);
          lv[r]  = 0.0625f * (rsr[r]*(Ct[tp][r] - mr[r]*su_c) + cb_c);
        }
        float a_[4];
        #pragma unroll
        for (int r = 0; r < 4; ++r) {
          float v = lv[r];
          v = fmaxf(v, __shfl_xor(v,1));
          v = fmaxf(v, __shfl_xor(v,2));
          v = fmaxf(v, __shfl_xor(v,4));
          v = fmaxf(v, __shfl_xor(v,8));
          const float e = __expf(lv[r] - v);
          float s = e;
          s += __shfl_xor(s,1);
          s += __shfl_xor(s,2);
          s += __shfl_xor(s,4);
          s += __shfl_xor(s,8);
          const float a = e / s;
          a_[r] = a;
          S_acc += a;
          R_acc += a * rsr[r] * mr[r];
          arr[4*tp + r] = a * rsr[r];
        }
        if (LAST) {
          float4v av = {a_[0], a_[1], a_[2], a_[3]};
          *reinterpret_cast<float4v*>(attn_out + (size_t)(b*KS + c)*NTOK + (size_t)(n0 + 8*g + 4*tp)) = av;
        }
      }
      bf16x8 afrag;
      #pragma unroll
      for (int j = 0; j < 8; ++j) afrag[j] = (__bf16)arr[j];

      #pragma unroll
      for (int t = 0; t < 16; ++t) {
        const unsigned int* rp = &myxl[(t*8 + (c>>1))*36 + 8*g];
        const uint4v q0 = *reinterpret_cast<const uint4v*>(rp);
        const uint4v q1 = *reinterpret_cast<const uint4v*>(rp + 4);
        const unsigned int sel = (c & 1) ? 0x07060302u : 0x05040100u;
        uint4v bd;
        bd[0] = __builtin_amdgcn_perm(q0[1], q0[0], sel);
        bd[1] = __builtin_amdgcn_perm(q0[3], q0[2], sel);
        bd[2] = __builtin_amdgcn_perm(q1[1], q1[0], sel);
        bd[3] = __builtin_amdgcn_perm(q1[3], q1[2], sel);
        const bf16x8 bfrag = __builtin_bit_cast(bf16x8, bd);
        Pacc[t] = __builtin_amdgcn_mfma_f32_16x16x32_bf16(afrag, bfrag, Pacc[t], 0, 0, 0);
      }
    }

    S_acc += __shfl_xor(S_acc,16); S_acc += __shfl_xor(S_acc,32);
    R_acc += __shfl_xor(R_acc,16); R_acc += __shfl_xor(R_acc,32);
    if (g == 0) { ssh[w][c] = S_acc; rsh[w][c] = R_acc; }

    float* pf = reinterpret_cast<float*>(arena) + w*4608;
    #pragma unroll
    for (int t = 0; t < 16; ++t) {
      #pragma unroll
      for (int r = 0; r < 4; ++r) pf[(4*g + r)*256 + t*16 + c] = Pacc[t][r];
    }
    __syncthreads();
    {
      float* outp = P_part + (size_t)blockIdx.x * (KS*DD);
      const float* p0 = reinterpret_cast<const float*>(arena);
      const float* p1 = p0 + 4608;
      const float* p2 = p0 + 9216;
      const float* p3 = p0 + 13824;
      for (int i = tid; i < KS*DD; i += 256) outp[i] = p0[i]+p1[i]+p2[i]+p3[i];
      if (tid < KS) {
        S_part[blockIdx.x*KS + tid] = ssh[0][tid]+ssh[1][tid]+ssh[2][tid]+ssh[3][tid];
        R_part[blockIdx.x*KS + tid] = rsh[0][tid]+rsh[1][tid]+rsh[2][tid]+rsh[3][tid];
      }
    }
    __syncthreads();
    if (tid < 4) {
      __threadfence();
      atomicExch(&flags[tid*(BB*NBLK) + blockIdx.x], tag);
    }
  }

  // ================= PHASE B: slot update (first 64 blocks) =================
  if (blockIdx.x >= BB*4) return;
  const int pb_b = blockIdx.x >> 2, k0 = (blockIdx.x & 3) * 4;
  const int gidx = blockIdx.x & 3;
  {
    if (tid < NBLK) {
      int* fp = &flags[gidx*(BB*NBLK) + pb_b*NBLK + tid];
      while (atomicAdd(fp, 0) != tag) { __builtin_amdgcn_s_sleep(2); }
    }
    __syncthreads();
    if (tid < NBLK) atomicExch(&flags[gidx*(BB*NBLK) + pb_b*NBLK + tid], 0);
    __threadfence();
  }

  float* Xs3 = reinterpret_cast<float*>(arena);            // [256][4] slots_in^T
  float* Ts  = reinterpret_cast<float*>(arena + 4096);     // [256][4] T -> y2^T -> Vs
  float* Us  = reinterpret_cast<float*>(arena + 8192);     // [256][4] upd^T -> Ys
  float* Pp  = reinterpret_cast<float*>(arena + 12288);    // [4][4][256] / [4][1024]
  float* Gi  = reinterpret_cast<float*>(arena + 28672);    // [4][768] -> Hs [1024][4]
  float* Gh  = reinterpret_cast<float*>(arena + 40960);    // [4][768] -> SUb
  float* Hp  = reinterpret_cast<float*>(arena + 53248);    // [4][256] -> CBb
  const int L = tid & 63;

  for (int i = tid; i < 4*DD; i += 256) {
    const int kk = i >> 8, cc = i & 255;
    Xs3[cc*4 + kk] = slots_in[(size_t)(pb_b*KS + k0 + kk)*DD + cc];
  }
  if (tid < 8) {
    const int kk = tid & 3;
    const float* srcp = (tid < 4) ? S_part : R_part;
    float s = 0.f;
    for (int p = 0; p < NBLK; ++p) s += srcp[(pb_b*NBLK + p)*KS + k0 + kk];
    ssh[0][tid] = s;
  }
  __syncthreads();
  for (int i = tid; i < 4*DD; i += 256) {
    const int kk = i >> 8, cc = i & 255;
    float P = 0.f;
    for (int p = 0; p < NBLK; ++p)
      P += P_part[(size_t)((pb_b*NBLK + p)*KS + k0 + kk)*DD + cc];
    const float S = ssh[0][kk], R = ssh[0][4+kk];
    Ts[cc*4 + kk] = (g_f[cc]*(P - R) + S*b_f[cc]) / (S + 1.0f);
  }
  __syncthreads();

  // upd = T @ Wv^T
  {
    float acc[4][4] = {};
    for (int cc = w*64; cc < w*64+64; ++cc) {
      const float4v xv = *reinterpret_cast<const float4v*>(Ts + cc*4);
      const uint2v wr = *reinterpret_cast<const uint2v*>(Wv_t + (size_t)cc*DD + 4*L);
      const float w0 = bflo(wr[0]), w1 = bfhi(wr[0]), w2 = bflo(wr[1]), w3 = bfhi(wr[1]);
      #pragma unroll
      for (int s = 0; s < 4; ++s) {
        acc[s][0] += xv[s]*w0; acc[s][1] += xv[s]*w1;
        acc[s][2] += xv[s]*w2; acc[s][3] += xv[s]*w3;
      }
    }
    #pragma unroll
    for (int s = 0; s < 4; ++s)
      *reinterpret_cast<float4v*>(Pp + (w*4+s)*256 + 4*L) = *reinterpret_cast<const float4v*>(acc[s]);
  }
  __syncthreads();
  for (int i = tid; i < 4*DD; i += 256) {
    const int kk = i >> 8, cc = i & 255;
    Us[cc*4 + kk] = Pp[(0*4+kk)*256+cc] + Pp[(1*4+kk)*256+cc] + Pp[(2*4+kk)*256+cc] + Pp[(3*4+kk)*256+cc];
  }
  __syncthreads();

  // GRU gates
  if (tid < 192) {
    const int j0 = tid * 4;
    float gia[4][4], gha[4][4];
    const float4v bi = *reinterpret_cast<const float4v*>(b_ih + j0);
    const float4v bh = *reinterpret_cast<const float4v*>(b_hh + j0);
    #pragma unroll
    for (int s = 0; s < 4; ++s)
      #pragma unroll
      for (int j = 0; j < 4; ++j) { gia[s][j] = bi[j]; gha[s][j] = bh[j]; }
    for (int cc = 0; cc < DD; ++cc) {
      const float4v xi = *reinterpret_cast<const float4v*>(Us + cc*4);
      const float4v xh = *reinterpret_cast<const float4v*>(Xs3 + cc*4);
      const uint2v wi = *reinterpret_cast<const uint2v*>(wih_t + (size_t)cc*768 + j0);
      const uint2v wh = *reinterpret_cast<const uint2v*>(whh_t + (size_t)cc*768 + j0);
      const float wi0 = bflo(wi[0]), wi1 = bfhi(wi[0]), wi2 = bflo(wi[1]), wi3 = bfhi(wi[1]);
      const float wh0 = bflo(wh[0]), wh1 = bfhi(wh[0]), wh2 = bflo(wh[1]), wh3 = bfhi(wh[1]);
      #pragma unroll
      for (int s = 0; s < 4; ++s) {
        gia[s][0] += xi[s]*wi0; gia[s][1] += xi[s]*wi1; gia[s][2] += xi[s]*wi2; gia[s][3] += xi[s]*wi3;
        gha[s][0] += xh[s]*wh0; gha[s][1] += xh[s]*wh1; gha[s][2] += xh[s]*wh2; gha[s][3] += xh[s]*wh3;
      }
    }
    #pragma unroll
    for (int s = 0; s < 4; ++s) {
      *reinterpret_cast<float4v*>(Gi + s*768 + j0) = *reinterpret_cast<const float4v*>(gia[s]);
      *reinterpret_cast<float4v*>(Gh + s*768 + j0) = *reinterpret_cast<const float4v*>(gha[s]);
    }
  }
  __syncthreads();
  for (int i = tid; i < 4*DD; i += 256) {
    const int kk = i >> 8, d = i & 255;
    const float r = 1.f/(1.f + __expf(-(Gi[kk*768+d] + Gh[kk*768+d])));
    const float z = 1.f/(1.f + __expf(-(Gi[kk*768+DD+d] + Gh[kk*768+DD+d])));
    const float n = tanhf(Gi[kk*768+2*DD+d] + r*Gh[kk*768+2*DD+d]);
    const float h = Xs3[d*4+kk];
    Hp[kk*256+d] = (1.f - z)*n + z*h;
  }
  __syncthreads();
  // y2 = LN(hp)*g_m + b_m -> Ts (transposed)
  {
    const float v0 = Hp[w*256+L], v1 = Hp[w*256+64+L], v2 = Hp[w*256+128+L], v3 = Hp[w*256+192+L];
    float s = v0+v1+v2+v3;
    #pragma unroll
    for (int m = 1; m < 64; m <<= 1) s += __shfl_xor(s, m);
    const float mean = s * (1.f/DD);
    const float d0 = v0-mean, d1 = v1-mean, d2 = v2-mean, d3 = v3-mean;
    float s2 = d0*d0 + d1*d1 + d2*d2 + d3*d3;
    #pragma unroll
    for (int m = 1; m < 64; m <<= 1) s2 += __shfl_xor(s2, m);
    const float rs = rsqrtf(s2 * (1.f/DD) + LN_EPS);
    Ts[L*4+w]       = d0*rs*g_m[L]      + b_m[L];
    Ts[(64+L)*4+w]  = d1*rs*g_m[64+L]   + b_m[64+L];
    Ts[(128+L)*4+w] = d2*rs*g_m[128+L]  + b_m[128+L];
    Ts[(192+L)*4+w] = d3*rs*g_m[192+L]  + b_m[192+L];
  }
  __syncthreads();

  // MLP1: hid = relu(y2 @ W1^T + b1) -> Pp as [4][1024]
  {
    const int j0 = tid * 4;
    float acc[4][4];
    const float4v bb = *reinterpret_cast<const float4v*>(b1 + j0);
    #pragma unroll
    for (int s = 0; s < 4; ++s)
      #pragma unroll
      for (int j = 0; j < 4; ++j) acc[s][j] = bb[j];
    for (int cc = 0; cc < DD; ++cc) {
      const float4v xv = *reinterpret_cast<const float4v*>(Ts + cc*4);
      const uint2v wr = *reinterpret_cast<const uint2v*>(W1_t + (size_t)cc*1024 + j0);
      const float w0 = bflo(wr[0]), w1 = bfhi(wr[0]), w2 = bflo(wr[1]), w3 = bfhi(wr[1]);
      #pragma unroll
      for (int s = 0; s < 4; ++s) {
        acc[s][0] += xv[s]*w0; acc[s][1] += xv[s]*w1;
        acc[s][2] += xv[s]*w2; acc[s][3] += xv[s]*w3;
      }
    }
    #pragma unroll
    for (int s = 0; s < 4; ++s) {
      float4v rv;
      #pragma unroll
      for (int j = 0; j < 4; ++j) rv[j] = fmaxf(acc[s][j], 0.f);
      *reinterpret_cast<float4v*>(Pp + s*1024 + j0) = rv;
    }
  }
  __syncthreads();
  {
    float* Hs = Gi;  // [1024][4], spans Gi and 4KB of Gh
    for (int i = tid; i < 4096; i += 256) {
      const int j = i & 1023, s = i >> 10;
      Hs[j*4 + s] = Pp[s*1024 + j];
    }
  }
  __syncthreads();
  // MLP2 -> Pp partials
  {
    const float* Hs = Gi;
    float acc[4][4] = {};
    for (int cc = w*256; cc < w*256+256; ++cc) {
      const float4v xv = *reinterpret_cast<const float4v*>(Hs + cc*4);
      const uint2v wr = *reinterpret_cast<const uint2v*>(W2_t + (size_t)cc*DD + 4*L);
      const float w0 = bflo(wr[0]), w1 = bfhi(wr[0]), w2 = bflo(wr[1]), w3 = bfhi(wr[1]);
      #pragma unroll
      for (int s = 0; s < 4; ++s) {
        acc[s][0] += xv[s]*w0; acc[s][1] += xv[s]*w1;
        acc[s][2] += xv[s]*w2; acc[s][3] += xv[s]*w3;
      }
    }
    #pragma unroll
    for (int s = 0; s < 4; ++s)
      *reinterpret_cast<float4v*>(Pp + (w*4+s)*256 + 4*L) = *reinterpret_cast<const float4v*>(acc[s]);
  }
  __syncthreads();
  // residual -> Vs (reuse Ts), write slots_next (+ out)
  for (int i = tid; i < 4*DD; i += 256) {
    const int kk = i >> 8, d = i & 255;
    const float v = Pp[(0*4+kk)*256+d] + Pp[(1*4+kk)*256+d] + Pp[(2*4+kk)*256+d] + Pp[(3*4+kk)*256+d]
                  + b2v[d] + Hp[kk*256+d];
    Ts[kk*256 + d] = v;   // Vs row-major [4][256]
    slots_next[(size_t)(pb_b*KS + k0 + kk)*DD + d] = v;
    if (LAST) out_slots[(size_t)(pb_b*KS + k0 + kk)*DD + d] = v;
  }
  __syncthreads();
  if constexpr (!LAST) {
    lnqu_tail_p(Ts, Us, Xs3, Pp, Gh, Hp, g_s, b_s, Wq_t, Wk_b, g_f, b_f,
                u_buf, su_buf, cb_buf, pb_b, k0, tid);
  }
}

// ---------------------------------------------------------------- host
extern "C" void kernel_launch(void* const* d_in, const int* in_sizes, int n_in,
                              void* d_out, int out_size, void* d_ws, size_t ws_size,
                              hipStream_t stream)
{
  const float* features   = (const float*)d_in[0];
  const float* slots_init = (const float*)d_in[1];
  const float* g_f = (const float*)d_in[2];
  const float* b_f = (const float*)d_in[3];
  const float* g_s = (const float*)d_in[4];
  const float* b_s = (const float*)d_in[5];
  const float* g_m = (const float*)d_in[6];
  const float* b_m = (const float*)d_in[7];
  const float* Wq  = (const float*)d_in[8];
  const float* Wk  = (const float*)d_in[9];
  const float* Wv  = (const float*)d_in[10];
  const float* w_ih = (const float*)d_in[11];
  const float* w_hh = (const float*)d_in[12];
  const float* b_ih = (const float*)d_in[13];
  const float* b_hh = (const float*)d_in[14];
  const float* W1  = (const float*)d_in[15];
  const float* b1  = (const float*)d_in[16];
  const float* W2  = (const float*)d_in[17];
  const float* b2  = (const float*)d_in[18];

  float* out_slots = (float*)d_out;
  float* out_attn  = out_slots + (size_t)BB*KS*DD;

  char* ws = (char*)d_ws;
  size_t off = 0;
  auto alloc = [&](size_t bytes) -> void* {
    void* p = ws + off;
    off += (bytes + 255) & ~(size_t)255;
    return p;
  };
  unsigned short* u_buf  = (unsigned short*)alloc((size_t)BB*KS*DD*2);
  float*          su_buf = (float*)alloc((size_t)BB*KS*4);
  float*          cb_buf = (float*)alloc((size_t)BB*KS*4);
  float*          P_part = (float*)alloc((size_t)BB*NBLK*KS*DD*4);
  float*          S_part = (float*)alloc((size_t)BB*NBLK*KS*4);
  float*          R_part = (float*)alloc((size_t)BB*NBLK*KS*4);
  float*          slots_ws = (float*)alloc((size_t)BB*KS*DD*4);
  int*            flags  = (int*)alloc((size_t)4*BB*NBLK*4);
  unsigned short* Wv_t  = (unsigned short*)alloc((size_t)256*256*2);
  unsigned short* wih_t = (unsigned short*)alloc((size_t)256*768*2);
  unsigned short* whh_t = (unsigned short*)alloc((size_t)256*768*2);
  unsigned short* W1_t  = (unsigned short*)alloc((size_t)256*1024*2);
  unsigned short* W2_t  = (unsigned short*)alloc((size_t)1024*256*2);
  unsigned short* Wq_t  = (unsigned short*)alloc((size_t)256*256*2);
  unsigned short* Wk_b  = (unsigned short*)alloc((size_t)256*256*2);
  float*          stats = (float*)alloc((size_t)BB*NTOK*2*4);
  unsigned short* xb    = (unsigned short*)alloc((size_t)BB*NTOK*FEATN*2);
  (void)in_sizes; (void)n_in; (void)out_size; (void)ws_size;

  prep_w_kernel<<<272, 256, 0, stream>>>(Wv, w_ih, w_hh, W1, W2, Wq, Wk,
                                         Wv_t, wih_t, whh_t, W1_t, W2_t, Wq_t, Wk_b);
  k0_kernel<<<BB*4, 256, 0, stream>>>(slots_init, g_s, b_s, Wq_t, Wk_b, g_f, b_f,
                                      u_buf, su_buf, cb_buf);

  iter_kernel<0,0><<<BB*NBLK, 256, 0, stream>>>(features, xb, stats, u_buf, su_buf, cb_buf,
      P_part, S_part, R_part, out_attn, slots_init, slots_ws,
      g_f, b_f, Wv_t, wih_t, whh_t, b_ih, b_hh, g_m, b_m, W1_t, b1, W2_t, b2,
      g_s, b_s, Wq_t, Wk_b, out_slots, flags, 1);
  iter_kernel<1,0><<<BB*NBLK, 256, 0, stream>>>(features, xb, stats, u_buf, su_buf, cb_buf,
      P_part, S_part, R_part, out_attn, slots_ws, slots_ws,
      g_f, b_f, Wv_t, wih_t, whh_t, b_ih, b_hh, g_m, b_m, W1_t, b1, W2_t, b2,
      g_s, b_s, Wq_t, Wk_b, out_slots, flags, 2);
  iter_kernel<1,1><<<BB*NBLK, 256, 0, stream>>>(features, xb, stats, u_buf, su_buf, cb_buf,
      P_part, S_part, R_part, out_attn, slots_ws, slots_ws,
      g_f, b_f, Wv_t, wih_t, whh_t, b_ih, b_hh, g_m, b_m, W1_t, b1, W2_t, b2,
      g_s, b_s, Wq_t, Wk_b, out_slots, flags, 3);
}

// Round 6
// 580.316 us; speedup vs baseline: 1.1667x; 1.1282x over previous
//
// SlotAttention fused forward for MI355X (gfx950) — round 6.
// r6 = r5 with the phaseB LDS-overflow bug fixed: the MLP hidden transpose
// (Hs = [1024][4] floats, 16KB) deliberately spans Gi(12KB)+4KB of Gh; r4/r5
// declared Gi/Gh/Hp as separate __shared__ arrays, so the overflow corrupted
// live LDS (Hp). Restored r3's explicit single-arena layout for phase B.
// Phase A unchanged from r5: r3's proven compute + register load-hoisting.
#include <hip/hip_runtime.h>
#include <cstdint>
#include <cstddef>

#define BB    16
#define NTOK  16384
#define KS    16
#define DD    256
#define FEATN 256
#define NBLK  32
#define LN_EPS 1e-5f

typedef float        float4v __attribute__((ext_vector_type(4)));
typedef unsigned int uint4v  __attribute__((ext_vector_type(4)));
typedef unsigned int uint2v  __attribute__((ext_vector_type(2)));
typedef __bf16       bf16x8  __attribute__((ext_vector_type(8)));

__device__ __forceinline__ float bflo(unsigned u){ return __builtin_bit_cast(float, u << 16); }
__device__ __forceinline__ float bfhi(unsigned u){ return __builtin_bit_cast(float, u & 0xffff0000u); }
__device__ __forceinline__ unsigned short f2bf(float v){ __bf16 b = (__bf16)v; return __builtin_bit_cast(unsigned short, b); }

// ---------------------------------------------------------------- weight prep
__global__ void prep_w_kernel(const float* __restrict__ Wv, const float* __restrict__ w_ih,
                              const float* __restrict__ w_hh, const float* __restrict__ W1,
                              const float* __restrict__ W2, const float* __restrict__ Wq,
                              const float* __restrict__ Wk,
                              unsigned short* __restrict__ Wv_t, unsigned short* __restrict__ wih_t,
                              unsigned short* __restrict__ whh_t, unsigned short* __restrict__ W1_t,
                              unsigned short* __restrict__ W2_t, unsigned short* __restrict__ Wq_t,
                              unsigned short* __restrict__ Wk_b)
{
  __shared__ float tile[64][65];
  const int t = blockIdx.x, tid = threadIdx.x;
  const float* src; unsigned short* dst; int R, C, base;
  if      (t < 16)  { src = Wv;   dst = Wv_t;  R = 256;  C = 256;  base = 0;   }
  else if (t < 64)  { src = w_ih; dst = wih_t; R = 768;  C = 256;  base = 16;  }
  else if (t < 112) { src = w_hh; dst = whh_t; R = 768;  C = 256;  base = 64;  }
  else if (t < 176) { src = W1;   dst = W1_t;  R = 1024; C = 256;  base = 112; }
  else if (t < 240) { src = W2;   dst = W2_t;  R = 256;  C = 1024; base = 176; }
  else if (t < 256) { src = Wq;   dst = Wq_t;  R = 256;  C = 256;  base = 240; }
  else {
    const int t2 = t - 256;
    for (int i = tid; i < 4096; i += 256) {
      const int idx = t2*4096 + i;
      Wk_b[idx] = f2bf(Wk[idx]);
    }
    return;
  }
  const int tt = t - base;
  const int tiles_r = R >> 6;
  const int r0 = (tt % tiles_r) * 64, c0 = (tt / tiles_r) * 64;
  const int j = tid & 63, i0 = (tid >> 6) * 16;
  for (int s = 0; s < 16; ++s)
    tile[i0 + s][j] = src[(size_t)(r0 + i0 + s)*C + c0 + j];
  __syncthreads();
  for (int s = 0; s < 16; ++s) {
    const int i = i0 + s;
    dst[(size_t)(c0 + i)*R + r0 + j] = f2bf(tile[j][i]);
  }
}

// ---------------------------------------------------------------- LN->q->u/su/cb tail
__device__ __forceinline__ void lnqu_tail_p(
    const float* Vs, float* Ys, float* Qs, float* Pp, float* SUb, float* CBb,
    const float* __restrict__ g_s, const float* __restrict__ b_s,
    const unsigned short* __restrict__ Wq_t, const unsigned short* __restrict__ Wk_b,
    const float* __restrict__ g_f, const float* __restrict__ b_f,
    unsigned short* __restrict__ u_buf, float* __restrict__ su_buf, float* __restrict__ cb_buf,
    int b, int k0, int tid)
{
  const int w = tid >> 6, L = tid & 63;
  {
    const float v0 = Vs[w*256+L], v1 = Vs[w*256+64+L], v2 = Vs[w*256+128+L], v3 = Vs[w*256+192+L];
    float s = v0+v1+v2+v3;
    #pragma unroll
    for (int m = 1; m < 64; m <<= 1) s += __shfl_xor(s, m);
    const float mean = s * (1.f/DD);
    const float d0 = v0-mean, d1 = v1-mean, d2 = v2-mean, d3 = v3-mean;
    float s2 = d0*d0 + d1*d1 + d2*d2 + d3*d3;
    #pragma unroll
    for (int m = 1; m < 64; m <<= 1) s2 += __shfl_xor(s2, m);
    const float rs = rsqrtf(s2 * (1.f/DD) + LN_EPS);
    Ys[L*4+w]       = d0*rs*g_s[L]      + b_s[L];
    Ys[(64+L)*4+w]  = d1*rs*g_s[64+L]   + b_s[64+L];
    Ys[(128+L)*4+w] = d2*rs*g_s[128+L]  + b_s[128+L];
    Ys[(192+L)*4+w] = d3*rs*g_s[192+L]  + b_s[192+L];
  }
  __syncthreads();
  {
    float acc[4][4] = {};
    for (int cc = w*64; cc < w*64+64; ++cc) {
      const float4v xv = *reinterpret_cast<const float4v*>(Ys + cc*4);
      const uint2v wr = *reinterpret_cast<const uint2v*>(Wq_t + (size_t)cc*DD + 4*L);
      const float w0 = bflo(wr[0]), w1 = bfhi(wr[0]), w2 = bflo(wr[1]), w3 = bfhi(wr[1]);
      #pragma unroll
      for (int s = 0; s < 4; ++s) {
        acc[s][0] += xv[s]*w0; acc[s][1] += xv[s]*w1;
        acc[s][2] += xv[s]*w2; acc[s][3] += xv[s]*w3;
      }
    }
    #pragma unroll
    for (int s = 0; s < 4; ++s)
      *reinterpret_cast<float4v*>(Pp + (w*4+s)*256 + 4*L) = *reinterpret_cast<const float4v*>(acc[s]);
  }
  __syncthreads();
  for (int i = tid; i < 4*DD; i += 256) {
    const int kk = i >> 8, d = i & 255;
    Qs[d*4+kk] = Pp[(0*4+kk)*256+d] + Pp[(1*4+kk)*256+d] + Pp[(2*4+kk)*256+d] + Pp[(3*4+kk)*256+d];
  }
  __syncthreads();
  {
    float acc[4][4] = {};
    for (int d = w*64; d < w*64+64; ++d) {
      const float4v xv = *reinterpret_cast<const float4v*>(Qs + d*4);
      const uint2v wr = *reinterpret_cast<const uint2v*>(Wk_b + (size_t)d*DD + 4*L);
      const float w0 = bflo(wr[0]), w1 = bfhi(wr[0]), w2 = bflo(wr[1]), w3 = bfhi(wr[1]);
      #pragma unroll
      for (int s = 0; s < 4; ++s) {
        acc[s][0] += xv[s]*w0; acc[s][1] += xv[s]*w1;
        acc[s][2] += xv[s]*w2; acc[s][3] += xv[s]*w3;
      }
    }
    #pragma unroll
    for (int s = 0; s < 4; ++s)
      *reinterpret_cast<float4v*>(Pp + (w*4+s)*256 + 4*L) = *reinterpret_cast<const float4v*>(acc[s]);
  }
  __syncthreads();
  for (int i = tid; i < 4*DD; i += 256) {
    const int kk = i >> 8, cc = i & 255;
    const float qk = Pp[(0*4+kk)*256+cc] + Pp[(1*4+kk)*256+cc] + Pp[(2*4+kk)*256+cc] + Pp[(3*4+kk)*256+cc];
    const float uv = qk * g_f[cc];
    u_buf[(size_t)(b*KS + k0 + kk)*DD + cc] = f2bf(uv);
    SUb[kk*256+cc] = uv;
    CBb[kk*256+cc] = qk * b_f[cc];
  }
  __syncthreads();
  {
    float s  = SUb[w*256+L] + SUb[w*256+64+L] + SUb[w*256+128+L] + SUb[w*256+192+L];
    float cv = CBb[w*256+L] + CBb[w*256+64+L] + CBb[w*256+128+L] + CBb[w*256+192+L];
    #pragma unroll
    for (int m = 1; m < 64; m <<= 1) { s += __shfl_xor(s, m); cv += __shfl_xor(cv, m); }
    if (L == 0) { su_buf[b*KS + k0 + w] = s; cb_buf[b*KS + k0 + w] = cv; }
  }
}

// ---------------------------------------------------------------- K0
__global__ void k0_kernel(const float* __restrict__ slots_init,
                          const float* __restrict__ g_s, const float* __restrict__ b_s,
                          const unsigned short* __restrict__ Wq_t, const unsigned short* __restrict__ Wk_b,
                          const float* __restrict__ g_f, const float* __restrict__ b_f,
                          unsigned short* __restrict__ u_buf, float* __restrict__ su_buf,
                          float* __restrict__ cb_buf)
{
  const int b = blockIdx.x >> 2, k0 = (blockIdx.x & 3) * 4;
  const int tid = threadIdx.x;
  __shared__ __align__(16) float Vs[4*DD];
  __shared__ __align__(16) float Ys[DD*4];
  __shared__ __align__(16) float Qs[DD*4];
  __shared__ __align__(16) float Pp[4*4*DD];
  __shared__ __align__(16) float SUb[4*DD];
  __shared__ __align__(16) float CBb[4*DD];
  for (int i = tid; i < 4*DD; i += 256)
    Vs[i] = slots_init[(size_t)(b*KS + k0)*DD + i];
  __syncthreads();
  lnqu_tail_p(Vs, Ys, Qs, Pp, SUb, CBb, g_s, b_s, Wq_t, Wk_b, g_f, b_f,
              u_buf, su_buf, cb_buf, b, k0, tid);
}

// ---------------------------------------------------------------- phase A (r3 compute + load hoisting)
template<int MODE, int LAST>
__launch_bounds__(256, 2)
__global__ void phaseA_kernel(const float* __restrict__ feat,
                              unsigned short* __restrict__ xb, float* __restrict__ stats,
                              const unsigned short* __restrict__ u_buf,
                              const float* __restrict__ su_buf,
                              const float* __restrict__ cb_buf,
                              float* __restrict__ P_part,
                              float* __restrict__ S_part,
                              float* __restrict__ R_part,
                              float* __restrict__ attn_out)
{
  __shared__ __align__(16) unsigned int xl[4][128*36];
  __shared__ float ssh[4][16];
  __shared__ float rsh[4][16];

  const int b   = blockIdx.x / NBLK;
  const int blk = blockIdx.x - b*NBLK;
  const int tid = threadIdx.x;
  const int w = tid >> 6;
  const int l = tid & 63;
  const int c = l & 15;
  const int g = l >> 4;

  bf16x8 ufrag[8];
  {
    const bf16x8* up = reinterpret_cast<const bf16x8*>(u_buf + (size_t)(b*KS + c)*DD);
    #pragma unroll
    for (int kk = 0; kk < 8; ++kk) ufrag[kk] = up[4*kk + g];
  }
  const float su_c = su_buf[b*KS + c];
  const float cb_c = cb_buf[b*KS + c];

  float4v Pacc[16];
  #pragma unroll
  for (int t = 0; t < 16; ++t) Pacc[t] = (float4v){0.f,0.f,0.f,0.f};
  float S_acc = 0.f, R_acc = 0.f;

  unsigned int* myxl = xl[w];
  const int rbase = 8*(c>>2) + (c&3);   // n_local = rbase + 4*tp

  for (int pass = 0; pass < 4; ++pass) {
    const int n0 = blk*(NTOK/NBLK) + pass*128 + w*32;
    float4v Ct[2];
    float m_t[2], rs_t[2];

    if constexpr (MODE == 1) {
      // hoist: both rows' 16 b128 loads + stats issued before any consume
      bf16x8 xr0[8], xr1[8];
      float2 st0, st1;
      {
        const size_t row0 = (size_t)b*NTOK + (size_t)(n0 + rbase);
        const size_t row1 = row0 + 4;
        const bf16x8* p0v = reinterpret_cast<const bf16x8*>(xb + row0*FEATN);
        const bf16x8* p1v = reinterpret_cast<const bf16x8*>(xb + row1*FEATN);
        #pragma unroll
        for (int kk = 0; kk < 8; ++kk) { xr0[kk] = p0v[4*kk + g]; xr1[kk] = p1v[4*kk + g]; }
        st0 = *reinterpret_cast<const float2*>(stats + row0*2);
        st1 = *reinterpret_cast<const float2*>(stats + row1*2);
      }
      #pragma unroll
      for (int tp = 0; tp < 2; ++tp) {
        const int nloc = rbase + 4*tp;
        float4v Cacc = (float4v){0.f,0.f,0.f,0.f};
        #pragma unroll
        for (int kk = 0; kk < 8; ++kk) {
          const bf16x8 af = tp ? xr1[kk] : xr0[kk];
          const uint4v ad = __builtin_bit_cast(uint4v, af);
          const int pb = (16*kk + 4*g)*36 + nloc;
          myxl[pb      ] = ad[0];
          myxl[pb + 36 ] = ad[1];
          myxl[pb + 72 ] = ad[2];
          myxl[pb + 108] = ad[3];
          Cacc = __builtin_amdgcn_mfma_f32_16x16x32_bf16(af, ufrag[kk], Cacc, 0, 0, 0);
        }
        m_t[tp]  = tp ? st1.x : st0.x;
        rs_t[tp] = tp ? st1.y : st0.y;
        Ct[tp]   = Cacc;
      }
    } else {
      #pragma unroll
      for (int tp = 0; tp < 2; ++tp) {
        const int nloc = rbase + 4*tp;
        const size_t row = (size_t)b*NTOK + (size_t)(n0 + nloc);
        const float* fr = feat + row*FEATN;
        float4v xf[16];
        #pragma unroll
        for (int kk = 0; kk < 8; ++kk) {
          xf[2*kk]   = *reinterpret_cast<const float4v*>(fr + 32*kk + 8*g);
          xf[2*kk+1] = *reinterpret_cast<const float4v*>(fr + 32*kk + 8*g + 4);
        }
        unsigned short* xw = xb + row*FEATN;
        float sum = 0.f, sq = 0.f;
        float4v Cacc = (float4v){0.f,0.f,0.f,0.f};
        #pragma unroll
        for (int kk = 0; kk < 8; ++kk) {
          const float4v x0 = xf[2*kk], x1 = xf[2*kk+1];
          sum += x0[0]+x0[1]+x0[2]+x0[3] + x1[0]+x1[1]+x1[2]+x1[3];
          sq  += x0[0]*x0[0]+x0[1]*x0[1]+x0[2]*x0[2]+x0[3]*x0[3]
               + x1[0]*x1[0]+x1[1]*x1[1]+x1[2]*x1[2]+x1[3]*x1[3];
          bf16x8 af;
          af[0]=(__bf16)x0[0]; af[1]=(__bf16)x0[1]; af[2]=(__bf16)x0[2]; af[3]=(__bf16)x0[3];
          af[4]=(__bf16)x1[0]; af[5]=(__bf16)x1[1]; af[6]=(__bf16)x1[2]; af[7]=(__bf16)x1[3];
          *reinterpret_cast<bf16x8*>(xw + 32*kk + 8*g) = af;
          const uint4v ad = __builtin_bit_cast(uint4v, af);
          const int pb = (16*kk + 4*g)*36 + nloc;
          myxl[pb      ] = ad[0];
          myxl[pb + 36 ] = ad[1];
          myxl[pb + 72 ] = ad[2];
          myxl[pb + 108] = ad[3];
          Cacc = __builtin_amdgcn_mfma_f32_16x16x32_bf16(af, ufrag[kk], Cacc, 0, 0, 0);
        }
        sum += __shfl_xor(sum,16); sum += __shfl_xor(sum,32);
        sq  += __shfl_xor(sq ,16); sq  += __shfl_xor(sq ,32);
        const float mean = sum * (1.f/FEATN);
        const float var  = sq  * (1.f/FEATN) - mean*mean;
        m_t[tp]  = mean;
        rs_t[tp] = rsqrtf(var + LN_EPS);
        float2 st; st.x = m_t[tp]; st.y = rs_t[tp];
        *reinterpret_cast<float2*>(stats + row*2) = st;
        Ct[tp] = Cacc;
      }
    }

    float arr[8];
    #pragma unroll
    for (int tp = 0; tp < 2; ++tp) {
      float lv[4], rsr[4], mr[4];
      #pragma unroll
      for (int r = 0; r < 4; ++r) {
        const int src = 4*g + r;
        rsr[r] = __shfl(rs_t[tp], src);
        mr[r]  = __shfl(m_t[tp],  src);
        lv[r]  = 0.0625f * (rsr[r]*(Ct[tp][r] - mr[r]*su_c) + cb_c);
      }
      float a_[4];
      #pragma unroll
      for (int r = 0; r < 4; ++r) {
        float v = lv[r];
        v = fmaxf(v, __shfl_xor(v,1));
        v = fmaxf(v, __shfl_xor(v,2));
        v = fmaxf(v, __shfl_xor(v,4));
        v = fmaxf(v, __shfl_xor(v,8));
        const float e = __expf(lv[r] - v);
        float s = e;
        s += __shfl_xor(s,1);
        s += __shfl_xor(s,2);
        s += __shfl_xor(s,4);
        s += __shfl_xor(s,8);
        const float a = e / s;
        a_[r] = a;
        S_acc += a;
        R_acc += a * rsr[r] * mr[r];
        arr[4*tp + r] = a * rsr[r];
      }
      if (LAST) {
        float4v av = {a_[0], a_[1], a_[2], a_[3]};
        *reinterpret_cast<float4v*>(attn_out + (size_t)(b*KS + c)*NTOK + (size_t)(n0 + 8*g + 4*tp)) = av;
      }
    }
    bf16x8 afrag;
    #pragma unroll
    for (int j = 0; j < 8; ++j) afrag[j] = (__bf16)arr[j];

    #pragma unroll
    for (int t = 0; t < 16; ++t) {
      const unsigned int* rp = &myxl[(t*8 + (c>>1))*36 + 8*g];
      const uint4v q0 = *reinterpret_cast<const uint4v*>(rp);
      const uint4v q1 = *reinterpret_cast<const uint4v*>(rp + 4);
      const unsigned int sel = (c & 1) ? 0x07060302u : 0x05040100u;
      uint4v bd;
      bd[0] = __builtin_amdgcn_perm(q0[1], q0[0], sel);
      bd[1] = __builtin_amdgcn_perm(q0[3], q0[2], sel);
      bd[2] = __builtin_amdgcn_perm(q1[1], q1[0], sel);
      bd[3] = __builtin_amdgcn_perm(q1[3], q1[2], sel);
      const bf16x8 bfrag = __builtin_bit_cast(bf16x8, bd);
      Pacc[t] = __builtin_amdgcn_mfma_f32_16x16x32_bf16(afrag, bfrag, Pacc[t], 0, 0, 0);
    }
  }

  S_acc += __shfl_xor(S_acc,16); S_acc += __shfl_xor(S_acc,32);
  R_acc += __shfl_xor(R_acc,16); R_acc += __shfl_xor(R_acc,32);
  if (g == 0) { ssh[w][c] = S_acc; rsh[w][c] = R_acc; }

  float* pf = reinterpret_cast<float*>(myxl);
  #pragma unroll
  for (int t = 0; t < 16; ++t) {
    #pragma unroll
    for (int r = 0; r < 4; ++r) pf[(4*g + r)*256 + t*16 + c] = Pacc[t][r];
  }
  __syncthreads();
  {
    float* outp = P_part + (size_t)blockIdx.x * (KS*DD);
    const float* p0 = reinterpret_cast<const float*>(&xl[0][0]);
    const float* p1 = p0 + 4608;
    const float* p2 = p0 + 9216;
    const float* p3 = p0 + 13824;
    for (int i = tid; i < KS*DD; i += 256) outp[i] = p0[i]+p1[i]+p2[i]+p3[i];
    if (tid < KS) {
      S_part[blockIdx.x*KS + tid] = ssh[0][tid]+ssh[1][tid]+ssh[2][tid]+ssh[3][tid];
      R_part[blockIdx.x*KS + tid] = rsh[0][tid]+rsh[1][tid]+rsh[2][tid]+rsh[3][tid];
    }
  }
}

// ---------------------------------------------------------------- phase B: slot update
// Explicit single-arena LDS layout (r3-identical): the MLP hidden transpose
// Hs=[1024][4] (16KB) deliberately spans Gi(12KB)+first 4KB of Gh (dead there).
template<int LAST>
__global__ void phaseB_kernel(const float* __restrict__ P_part, const float* __restrict__ S_part,
                              const float* __restrict__ R_part, const float* __restrict__ slots_in,
                              const float* __restrict__ g_f, const float* __restrict__ b_f,
                              const unsigned short* __restrict__ Wv_t,
                              const unsigned short* __restrict__ wih_t,
                              const unsigned short* __restrict__ whh_t,
                              const float* __restrict__ b_ih, const float* __restrict__ b_hh,
                              const float* __restrict__ g_m, const float* __restrict__ b_m,
                              const unsigned short* __restrict__ W1_t, const float* __restrict__ b1,
                              const unsigned short* __restrict__ W2_t, const float* __restrict__ b2v,
                              const float* __restrict__ g_s, const float* __restrict__ b_s,
                              const unsigned short* __restrict__ Wq_t,
                              const unsigned short* __restrict__ Wk_b,
                              float* __restrict__ slots_next, float* __restrict__ out_slots,
                              unsigned short* __restrict__ u_buf, float* __restrict__ su_buf,
                              float* __restrict__ cb_buf)
{
  const int pb_b = blockIdx.x >> 2, k0 = (blockIdx.x & 3) * 4;
  const int tid = threadIdx.x;
  const int w = tid >> 6, L = tid & 63;

  __shared__ __align__(16) char arena[57344];
  __shared__ float SRred[8][17];
  __shared__ float SRf[8];

  float* Xs3 = reinterpret_cast<float*>(arena);            // [256][4] slots_in^T
  float* Ts  = reinterpret_cast<float*>(arena + 4096);     // [256][4] T^T -> y2^T -> Vs
  float* Us  = reinterpret_cast<float*>(arena + 8192);     // [256][4] upd^T -> Ys
  float* Pp  = reinterpret_cast<float*>(arena + 12288);    // [16][256] partials / [4][1024] hid
  float* Gi  = reinterpret_cast<float*>(arena + 28672);    // [4][768]; Hs=[1024][4] spans +4KB
  float* Gh  = reinterpret_cast<float*>(arena + 40960);    // [4][768] -> SUb
  float* Hp  = reinterpret_cast<float*>(arena + 53248);    // [4][256] -> CBb

  for (int i = tid; i < 4*DD; i += 256) {
    const int kk = i >> 8, cc = i & 255;
    Xs3[cc*4 + kk] = slots_in[(size_t)(pb_b*KS + k0 + kk)*DD + cc];
  }
  if (tid < 128) {
    const int which = tid >> 6, kk2 = (tid >> 4) & 3, pg = tid & 15;
    const float* srcp = which ? R_part : S_part;
    float s = 0.f;
    for (int p = pg; p < NBLK; p += 16) s += srcp[(pb_b*NBLK + p)*KS + k0 + kk2];
    SRred[which*4 + kk2][pg] = s;
  }
  __syncthreads();
  if (tid < 8) {
    float s = 0.f;
    #pragma unroll
    for (int i = 0; i < 16; ++i) s += SRred[tid][i];
    SRf[tid] = s;
  }
  __syncthreads();

  {
    const int kk = tid >> 6, c4 = (tid & 63) * 4;
    const float* base = P_part + ((size_t)(pb_b*NBLK)*KS + (size_t)(k0 + kk))*DD + c4;
    float4v a0 = (float4v){0,0,0,0}, a1 = a0, a2 = a0, a3 = a0;
    #pragma unroll 2
    for (int p = 0; p < NBLK; p += 4) {
      a0 += *reinterpret_cast<const float4v*>(base + (size_t)(p+0)*KS*DD);
      a1 += *reinterpret_cast<const float4v*>(base + (size_t)(p+1)*KS*DD);
      a2 += *reinterpret_cast<const float4v*>(base + (size_t)(p+2)*KS*DD);
      a3 += *reinterpret_cast<const float4v*>(base + (size_t)(p+3)*KS*DD);
    }
    const float4v P4 = (a0 + a1) + (a2 + a3);
    const float S = SRf[kk], R = SRf[4 + kk];
    const float inv = 1.f / (S + 1.f);
    const float4v gf4 = *reinterpret_cast<const float4v*>(g_f + c4);
    const float4v bf4 = *reinterpret_cast<const float4v*>(b_f + c4);
    #pragma unroll
    for (int j = 0; j < 4; ++j)
      Ts[(c4 + j)*4 + kk] = (gf4[j]*(P4[j] - R) + S*bf4[j]) * inv;
  }
  __syncthreads();

  // upd = T @ Wv^T
  {
    float acc[4][4] = {};
    for (int cc = w*64; cc < w*64+64; ++cc) {
      const float4v xv = *reinterpret_cast<const float4v*>(Ts + cc*4);
      const uint2v wr = *reinterpret_cast<const uint2v*>(Wv_t + (size_t)cc*DD + 4*L);
      const float w0 = bflo(wr[0]), w1 = bfhi(wr[0]), w2 = bflo(wr[1]), w3 = bfhi(wr[1]);
      #pragma unroll
      for (int s = 0; s < 4; ++s) {
        acc[s][0] += xv[s]*w0; acc[s][1] += xv[s]*w1;
        acc[s][2] += xv[s]*w2; acc[s][3] += xv[s]*w3;
      }
    }
    #pragma unroll
    for (int s = 0; s < 4; ++s)
      *reinterpret_cast<float4v*>(Pp + (w*4+s)*256 + 4*L) = *reinterpret_cast<const float4v*>(acc[s]);
  }
  __syncthreads();
  for (int i = tid; i < 4*DD; i += 256) {
    const int kk = i >> 8, cc = i & 255;
    Us[cc*4 + kk] = Pp[(0*4+kk)*256+cc] + Pp[(1*4+kk)*256+cc] + Pp[(2*4+kk)*256+cc] + Pp[(3*4+kk)*256+cc];
  }
  __syncthreads();

  // GRU gates
  if (tid < 192) {
    const int j0 = tid * 4;
    float gia[4][4], gha[4][4];
    const float4v bi = *reinterpret_cast<const float4v*>(b_ih + j0);
    const float4v bh = *reinterpret_cast<const float4v*>(b_hh + j0);
    #pragma unroll
    for (int s = 0; s < 4; ++s)
      #pragma unroll
      for (int j = 0; j < 4; ++j) { gia[s][j] = bi[j]; gha[s][j] = bh[j]; }
    for (int cc = 0; cc < DD; ++cc) {
      const float4v xi = *reinterpret_cast<const float4v*>(Us + cc*4);
      const float4v xh = *reinterpret_cast<const float4v*>(Xs3 + cc*4);
      const uint2v wi = *reinterpret_cast<const uint2v*>(wih_t + (size_t)cc*768 + j0);
      const uint2v wh = *reinterpret_cast<const uint2v*>(whh_t + (size_t)cc*768 + j0);
      const float wi0 = bflo(wi[0]), wi1 = bfhi(wi[0]), wi2 = bflo(wi[1]), wi3 = bfhi(wi[1]);
      const float wh0 = bflo(wh[0]), wh1 = bfhi(wh[0]), wh2 = bflo(wh[1]), wh3 = bfhi(wh[1]);
      #pragma unroll
      for (int s = 0; s < 4; ++s) {
        gia[s][0] += xi[s]*wi0; gia[s][1] += xi[s]*wi1; gia[s][2] += xi[s]*wi2; gia[s][3] += xi[s]*wi3;
        gha[s][0] += xh[s]*wh0; gha[s][1] += xh[s]*wh1; gha[s][2] += xh[s]*wh2; gha[s][3] += xh[s]*wh3;
      }
    }
    #pragma unroll
    for (int s = 0; s < 4; ++s) {
      *reinterpret_cast<float4v*>(Gi + s*768 + j0) = *reinterpret_cast<const float4v*>(gia[s]);
      *reinterpret_cast<float4v*>(Gh + s*768 + j0) = *reinterpret_cast<const float4v*>(gha[s]);
    }
  }
  __syncthreads();
  for (int i = tid; i < 4*DD; i += 256) {
    const int kk = i >> 8, d = i & 255;
    const float r = 1.f/(1.f + __expf(-(Gi[kk*768+d] + Gh[kk*768+d])));
    const float z = 1.f/(1.f + __expf(-(Gi[kk*768+DD+d] + Gh[kk*768+DD+d])));
    const float n = tanhf(Gi[kk*768+2*DD+d] + r*Gh[kk*768+2*DD+d]);
    const float h = Xs3[d*4+kk];
    Hp[kk*256+d] = (1.f - z)*n + z*h;
  }
  __syncthreads();
  {
    const float v0 = Hp[w*256+L], v1 = Hp[w*256+64+L], v2 = Hp[w*256+128+L], v3 = Hp[w*256+192+L];
    float s = v0+v1+v2+v3;
    #pragma unroll
    for (int m = 1; m < 64; m <<= 1) s += __shfl_xor(s, m);
    const float mean = s * (1.f/DD);
    const float d0 = v0-mean, d1 = v1-mean, d2 = v2-mean, d3 = v3-mean;
    float s2 = d0*d0 + d1*d1 + d2*d2 + d3*d3;
    #pragma unroll
    for (int m = 1; m < 64; m <<= 1) s2 += __shfl_xor(s2, m);
    const float rs = rsqrtf(s2 * (1.f/DD) + LN_EPS);
    Ts[L*4+w]       = d0*rs*g_m[L]      + b_m[L];
    Ts[(64+L)*4+w]  = d1*rs*g_m[64+L]   + b_m[64+L];
    Ts[(128+L)*4+w] = d2*rs*g_m[128+L]  + b_m[128+L];
    Ts[(192+L)*4+w] = d3*rs*g_m[192+L]  + b_m[192+L];
  }
  __syncthreads();

  // MLP1 -> Pp as [4][1024]
  {
    const int j0 = tid * 4;
    float acc[4][4];
    const float4v bb = *reinterpret_cast<const float4v*>(b1 + j0);
    #pragma unroll
    for (int s = 0; s < 4; ++s)
      #pragma unroll
      for (int j = 0; j < 4; ++j) acc[s][j] = bb[j];
    for (int cc = 0; cc < DD; ++cc) {
      const float4v xv = *reinterpret_cast<const float4v*>(Ts + cc*4);
      const uint2v wr = *reinterpret_cast<const uint2v*>(W1_t + (size_t)cc*1024 + j0);
      const float w0 = bflo(wr[0]), w1 = bfhi(wr[0]), w2 = bflo(wr[1]), w3 = bfhi(wr[1]);
      #pragma unroll
      for (int s = 0; s < 4; ++s) {
        acc[s][0] += xv[s]*w0; acc[s][1] += xv[s]*w1;
        acc[s][2] += xv[s]*w2; acc[s][3] += xv[s]*w3;
      }
    }
    #pragma unroll
    for (int s = 0; s < 4; ++s) {
      float4v rv;
      #pragma unroll
      for (int j = 0; j < 4; ++j) rv[j] = fmaxf(acc[s][j], 0.f);
      *reinterpret_cast<float4v*>(Pp + s*1024 + j0) = rv;
    }
  }
  __syncthreads();
  {
    float* Hs = Gi;  // [1024][4]: spans Gi + first 4KB of Gh (gate data dead)
    for (int i = tid; i < 4096; i += 256) {
      const int j = i & 1023, s = i >> 10;
      Hs[j*4 + s] = Pp[s*1024 + j];
    }
  }
  __syncthreads();
  // MLP2
  {
    const float* Hs = Gi;
    float acc[4][4] = {};
    for (int cc = w*256; cc < w*256+256; ++cc) {
      const float4v xv = *reinterpret_cast<const float4v*>(Hs + cc*4);
      const uint2v wr = *reinterpret_cast<const uint2v*>(W2_t + (size_t)cc*DD + 4*L);
      const float w0 = bflo(wr[0]), w1 = bfhi(wr[0]), w2 = bflo(wr[1]), w3 = bfhi(wr[1]);
      #pragma unroll
      for (int s = 0; s < 4; ++s) {
        acc[s][0] += xv[s]*w0; acc[s][1] += xv[s]*w1;
        acc[s][2] += xv[s]*w2; acc[s][3] += xv[s]*w3;
      }
    }
    #pragma unroll
    for (int s = 0; s < 4; ++s)
      *reinterpret_cast<float4v*>(Pp + (w*4+s)*256 + 4*L) = *reinterpret_cast<const float4v*>(acc[s]);
  }
  __syncthreads();
  for (int i = tid; i < 4*DD; i += 256) {
    const int kk = i >> 8, d = i & 255;
    const float v = Pp[(0*4+kk)*256+d] + Pp[(1*4+kk)*256+d] + Pp[(2*4+kk)*256+d] + Pp[(3*4+kk)*256+d]
                  + b2v[d] + Hp[kk*256+d];
    Ts[kk*256 + d] = v;   // Vs row-major [4][256]
    slots_next[(size_t)(pb_b*KS + k0 + kk)*DD + d] = v;
    if (LAST) out_slots[(size_t)(pb_b*KS + k0 + kk)*DD + d] = v;
  }
  __syncthreads();
  if constexpr (!LAST) {
    lnqu_tail_p(Ts, Us, Xs3, Pp, Gh, Hp, g_s, b_s, Wq_t, Wk_b, g_f, b_f,
                u_buf, su_buf, cb_buf, pb_b, k0, tid);
  }
}

// ---------------------------------------------------------------- host
extern "C" void kernel_launch(void* const* d_in, const int* in_sizes, int n_in,
                              void* d_out, int out_size, void* d_ws, size_t ws_size,
                              hipStream_t stream)
{
  const float* features   = (const float*)d_in[0];
  const float* slots_init = (const float*)d_in[1];
  const float* g_f = (const float*)d_in[2];
  const float* b_f = (const float*)d_in[3];
  const float* g_s = (const float*)d_in[4];
  const float* b_s = (const float*)d_in[5];
  const float* g_m = (const float*)d_in[6];
  const float* b_m = (const float*)d_in[7];
  const float* Wq  = (const float*)d_in[8];
  const float* Wk  = (const float*)d_in[9];
  const float* Wv  = (const float*)d_in[10];
  const float* w_ih = (const float*)d_in[11];
  const float* w_hh = (const float*)d_in[12];
  const float* b_ih = (const float*)d_in[13];
  const float* b_hh = (const float*)d_in[14];
  const float* W1  = (const float*)d_in[15];
  const float* b1  = (const float*)d_in[16];
  const float* W2  = (const float*)d_in[17];
  const float* b2  = (const float*)d_in[18];

  float* out_slots = (float*)d_out;
  float* out_attn  = out_slots + (size_t)BB*KS*DD;

  char* ws = (char*)d_ws;
  size_t off = 0;
  auto alloc = [&](size_t bytes) -> void* {
    void* p = ws + off;
    off += (bytes + 255) & ~(size_t)255;
    return p;
  };
  unsigned short* u_buf  = (unsigned short*)alloc((size_t)BB*KS*DD*2);
  float*          su_buf = (float*)alloc((size_t)BB*KS*4);
  float*          cb_buf = (float*)alloc((size_t)BB*KS*4);
  float*          P_part = (float*)alloc((size_t)BB*NBLK*KS*DD*4);
  float*          S_part = (float*)alloc((size_t)BB*NBLK*KS*4);
  float*          R_part = (float*)alloc((size_t)BB*NBLK*KS*4);
  float*          slots_ws = (float*)alloc((size_t)BB*KS*DD*4);
  unsigned short* Wv_t  = (unsigned short*)alloc((size_t)256*256*2);
  unsigned short* wih_t = (unsigned short*)alloc((size_t)256*768*2);
  unsigned short* whh_t = (unsigned short*)alloc((size_t)256*768*2);
  unsigned short* W1_t  = (unsigned short*)alloc((size_t)256*1024*2);
  unsigned short* W2_t  = (unsigned short*)alloc((size_t)1024*256*2);
  unsigned short* Wq_t  = (unsigned short*)alloc((size_t)256*256*2);
  unsigned short* Wk_b  = (unsigned short*)alloc((size_t)256*256*2);
  float*          stats = (float*)alloc((size_t)BB*NTOK*2*4);
  unsigned short* xb    = (unsigned short*)alloc((size_t)BB*NTOK*FEATN*2);
  (void)in_sizes; (void)n_in; (void)out_size; (void)ws_size;

  prep_w_kernel<<<272, 256, 0, stream>>>(Wv, w_ih, w_hh, W1, W2, Wq, Wk,
                                         Wv_t, wih_t, whh_t, W1_t, W2_t, Wq_t, Wk_b);
  k0_kernel<<<BB*4, 256, 0, stream>>>(slots_init, g_s, b_s, Wq_t, Wk_b, g_f, b_f,
                                      u_buf, su_buf, cb_buf);

  phaseA_kernel<0,0><<<BB*NBLK, 256, 0, stream>>>(features, xb, stats, u_buf, su_buf, cb_buf,
                                                  P_part, S_part, R_part, out_attn);
  phaseB_kernel<0><<<BB*4, 256, 0, stream>>>(P_part, S_part, R_part, slots_init, g_f, b_f,
                                             Wv_t, wih_t, whh_t, b_ih, b_hh, g_m, b_m,
                                             W1_t, b1, W2_t, b2, g_s, b_s, Wq_t, Wk_b,
                                             slots_ws, out_slots, u_buf, su_buf, cb_buf);
  phaseA_kernel<1,0><<<BB*NBLK, 256, 0, stream>>>(features, xb, stats, u_buf, su_buf, cb_buf,
                                                  P_part, S_part, R_part, out_attn);
  phaseB_kernel<0><<<BB*4, 256, 0, stream>>>(P_part, S_part, R_part, slots_ws, g_f, b_f,
                                             Wv_t, wih_t, whh_t, b_ih, b_hh, g_m, b_m,
                                             W1_t, b1, W2_t, b2, g_s, b_s, Wq_t, Wk_b,
                                             slots_ws, out_slots, u_buf, su_buf, cb_buf);
  phaseA_kernel<1,1><<<BB*NBLK, 256, 0, stream>>>(features, xb, stats, u_buf, su_buf, cb_buf,
                                                  P_part, S_part, R_part, out_attn);
  phaseB_kernel<1><<<BB*4, 256, 0, stream>>>(P_part, S_part, R_part, slots_ws, g_f, b_f,
                                             Wv_t, wih_t, whh_t, b_ih, b_hh, g_m, b_m,
                                             W1_t, b1, W2_t, b2, g_s, b_s, Wq_t, Wk_b,
                                             slots_ws, out_slots, u_buf, su_buf, cb_buf);
}

// Round 7
// 407.190 us; speedup vs baseline: 1.6627x; 1.4252x over previous
//
// SlotAttention fused forward for MI355X (gfx950) — round 7.
// r7 = r6 with the slot-update path (phaseB) rewritten for parallelism:
// the whole chain T->Wv->GRU->LN->MLP->residual is independent per (b,slot),
// so fusedB uses grid=256 blocks (one slot each; r6 used 64 blocks => 25% of
// CUs, 170us each, 96% stall). K is split across the 4 waves (64-iter loops,
// LDS partial combine). LDS arena is strictly non-overlapping (r4/r5 lesson).
// Next-iter LN->q->u runs in the proven k0_kernel on slots_ws. phaseA unchanged.
#include <hip/hip_runtime.h>
#include <cstdint>
#include <cstddef>

#define BB    16
#define NTOK  16384
#define KS    16
#define DD    256
#define FEATN 256
#define NBLK  32
#define LN_EPS 1e-5f

typedef float        float4v __attribute__((ext_vector_type(4)));
typedef unsigned int uint4v  __attribute__((ext_vector_type(4)));
typedef unsigned int uint2v  __attribute__((ext_vector_type(2)));
typedef __bf16       bf16x8  __attribute__((ext_vector_type(8)));

__device__ __forceinline__ float bflo(unsigned u){ return __builtin_bit_cast(float, u << 16); }
__device__ __forceinline__ float bfhi(unsigned u){ return __builtin_bit_cast(float, u & 0xffff0000u); }
__device__ __forceinline__ unsigned short f2bf(float v){ __bf16 b = (__bf16)v; return __builtin_bit_cast(unsigned short, b); }
__device__ __forceinline__ float sigm(float x){ return 1.f/(1.f + __expf(-x)); }

// ---------------------------------------------------------------- weight prep
__global__ void prep_w_kernel(const float* __restrict__ Wv, const float* __restrict__ w_ih,
                              const float* __restrict__ w_hh, const float* __restrict__ W1,
                              const float* __restrict__ W2, const float* __restrict__ Wq,
                              const float* __restrict__ Wk,
                              unsigned short* __restrict__ Wv_t, unsigned short* __restrict__ wih_t,
                              unsigned short* __restrict__ whh_t, unsigned short* __restrict__ W1_t,
                              unsigned short* __restrict__ W2_t, unsigned short* __restrict__ Wq_t,
                              unsigned short* __restrict__ Wk_b)
{
  __shared__ float tile[64][65];
  const int t = blockIdx.x, tid = threadIdx.x;
  const float* src; unsigned short* dst; int R, C, base;
  if      (t < 16)  { src = Wv;   dst = Wv_t;  R = 256;  C = 256;  base = 0;   }
  else if (t < 64)  { src = w_ih; dst = wih_t; R = 768;  C = 256;  base = 16;  }
  else if (t < 112) { src = w_hh; dst = whh_t; R = 768;  C = 256;  base = 64;  }
  else if (t < 176) { src = W1;   dst = W1_t;  R = 1024; C = 256;  base = 112; }
  else if (t < 240) { src = W2;   dst = W2_t;  R = 256;  C = 1024; base = 176; }
  else if (t < 256) { src = Wq;   dst = Wq_t;  R = 256;  C = 256;  base = 240; }
  else {
    const int t2 = t - 256;
    for (int i = tid; i < 4096; i += 256) {
      const int idx = t2*4096 + i;
      Wk_b[idx] = f2bf(Wk[idx]);
    }
    return;
  }
  const int tt = t - base;
  const int tiles_r = R >> 6;
  const int r0 = (tt % tiles_r) * 64, c0 = (tt / tiles_r) * 64;
  const int j = tid & 63, i0 = (tid >> 6) * 16;
  for (int s = 0; s < 16; ++s)
    tile[i0 + s][j] = src[(size_t)(r0 + i0 + s)*C + c0 + j];
  __syncthreads();
  for (int s = 0; s < 16; ++s) {
    const int i = i0 + s;
    dst[(size_t)(c0 + i)*R + r0 + j] = f2bf(tile[j][i]);
  }
}

// ---------------------------------------------------------------- LN->q->u/su/cb tail
__device__ __forceinline__ void lnqu_tail_p(
    const float* Vs, float* Ys, float* Qs, float* Pp, float* SUb, float* CBb,
    const float* __restrict__ g_s, const float* __restrict__ b_s,
    const unsigned short* __restrict__ Wq_t, const unsigned short* __restrict__ Wk_b,
    const float* __restrict__ g_f, const float* __restrict__ b_f,
    unsigned short* __restrict__ u_buf, float* __restrict__ su_buf, float* __restrict__ cb_buf,
    int b, int k0, int tid)
{
  const int w = tid >> 6, L = tid & 63;
  {
    const float v0 = Vs[w*256+L], v1 = Vs[w*256+64+L], v2 = Vs[w*256+128+L], v3 = Vs[w*256+192+L];
    float s = v0+v1+v2+v3;
    #pragma unroll
    for (int m = 1; m < 64; m <<= 1) s += __shfl_xor(s, m);
    const float mean = s * (1.f/DD);
    const float d0 = v0-mean, d1 = v1-mean, d2 = v2-mean, d3 = v3-mean;
    float s2 = d0*d0 + d1*d1 + d2*d2 + d3*d3;
    #pragma unroll
    for (int m = 1; m < 64; m <<= 1) s2 += __shfl_xor(s2, m);
    const float rs = rsqrtf(s2 * (1.f/DD) + LN_EPS);
    Ys[L*4+w]       = d0*rs*g_s[L]      + b_s[L];
    Ys[(64+L)*4+w]  = d1*rs*g_s[64+L]   + b_s[64+L];
    Ys[(128+L)*4+w] = d2*rs*g_s[128+L]  + b_s[128+L];
    Ys[(192+L)*4+w] = d3*rs*g_s[192+L]  + b_s[192+L];
  }
  __syncthreads();
  {
    float acc[4][4] = {};
    for (int cc = w*64; cc < w*64+64; ++cc) {
      const float4v xv = *reinterpret_cast<const float4v*>(Ys + cc*4);
      const uint2v wr = *reinterpret_cast<const uint2v*>(Wq_t + (size_t)cc*DD + 4*L);
      const float w0 = bflo(wr[0]), w1 = bfhi(wr[0]), w2 = bflo(wr[1]), w3 = bfhi(wr[1]);
      #pragma unroll
      for (int s = 0; s < 4; ++s) {
        acc[s][0] += xv[s]*w0; acc[s][1] += xv[s]*w1;
        acc[s][2] += xv[s]*w2; acc[s][3] += xv[s]*w3;
      }
    }
    #pragma unroll
    for (int s = 0; s < 4; ++s)
      *reinterpret_cast<float4v*>(Pp + (w*4+s)*256 + 4*L) = *reinterpret_cast<const float4v*>(acc[s]);
  }
  __syncthreads();
  for (int i = tid; i < 4*DD; i += 256) {
    const int kk = i >> 8, d = i & 255;
    Qs[d*4+kk] = Pp[(0*4+kk)*256+d] + Pp[(1*4+kk)*256+d] + Pp[(2*4+kk)*256+d] + Pp[(3*4+kk)*256+d];
  }
  __syncthreads();
  {
    float acc[4][4] = {};
    for (int d = w*64; d < w*64+64; ++d) {
      const float4v xv = *reinterpret_cast<const float4v*>(Qs + d*4);
      const uint2v wr = *reinterpret_cast<const uint2v*>(Wk_b + (size_t)d*DD + 4*L);
      const float w0 = bflo(wr[0]), w1 = bfhi(wr[0]), w2 = bflo(wr[1]), w3 = bfhi(wr[1]);
      #pragma unroll
      for (int s = 0; s < 4; ++s) {
        acc[s][0] += xv[s]*w0; acc[s][1] += xv[s]*w1;
        acc[s][2] += xv[s]*w2; acc[s][3] += xv[s]*w3;
      }
    }
    #pragma unroll
    for (int s = 0; s < 4; ++s)
      *reinterpret_cast<float4v*>(Pp + (w*4+s)*256 + 4*L) = *reinterpret_cast<const float4v*>(acc[s]);
  }
  __syncthreads();
  for (int i = tid; i < 4*DD; i += 256) {
    const int kk = i >> 8, cc = i & 255;
    const float qk = Pp[(0*4+kk)*256+cc] + Pp[(1*4+kk)*256+cc] + Pp[(2*4+kk)*256+cc] + Pp[(3*4+kk)*256+cc];
    const float uv = qk * g_f[cc];
    u_buf[(size_t)(b*KS + k0 + kk)*DD + cc] = f2bf(uv);
    SUb[kk*256+cc] = uv;
    CBb[kk*256+cc] = qk * b_f[cc];
  }
  __syncthreads();
  {
    float s  = SUb[w*256+L] + SUb[w*256+64+L] + SUb[w*256+128+L] + SUb[w*256+192+L];
    float cv = CBb[w*256+L] + CBb[w*256+64+L] + CBb[w*256+128+L] + CBb[w*256+192+L];
    #pragma unroll
    for (int m = 1; m < 64; m <<= 1) { s += __shfl_xor(s, m); cv += __shfl_xor(cv, m); }
    if (L == 0) { su_buf[b*KS + k0 + w] = s; cb_buf[b*KS + k0 + w] = cv; }
  }
}

// ---------------------------------------------------------------- K0 (also the next-iter tail)
__global__ void k0_kernel(const float* __restrict__ slots_init,
                          const float* __restrict__ g_s, const float* __restrict__ b_s,
                          const unsigned short* __restrict__ Wq_t, const unsigned short* __restrict__ Wk_b,
                          const float* __restrict__ g_f, const float* __restrict__ b_f,
                          unsigned short* __restrict__ u_buf, float* __restrict__ su_buf,
                          float* __restrict__ cb_buf)
{
  const int b = blockIdx.x >> 2, k0 = (blockIdx.x & 3) * 4;
  const int tid = threadIdx.x;
  __shared__ __align__(16) float Vs[4*DD];
  __shared__ __align__(16) float Ys[DD*4];
  __shared__ __align__(16) float Qs[DD*4];
  __shared__ __align__(16) float Pp[4*4*DD];
  __shared__ __align__(16) float SUb[4*DD];
  __shared__ __align__(16) float CBb[4*DD];
  for (int i = tid; i < 4*DD; i += 256)
    Vs[i] = slots_init[(size_t)(b*KS + k0)*DD + i];
  __syncthreads();
  lnqu_tail_p(Vs, Ys, Qs, Pp, SUb, CBb, g_s, b_s, Wq_t, Wk_b, g_f, b_f,
              u_buf, su_buf, cb_buf, b, k0, tid);
}

// ---------------------------------------------------------------- phase A (unchanged, r6-passing)
template<int MODE, int LAST>
__launch_bounds__(256, 2)
__global__ void phaseA_kernel(const float* __restrict__ feat,
                              unsigned short* __restrict__ xb, float* __restrict__ stats,
                              const unsigned short* __restrict__ u_buf,
                              const float* __restrict__ su_buf,
                              const float* __restrict__ cb_buf,
                              float* __restrict__ P_part,
                              float* __restrict__ S_part,
                              float* __restrict__ R_part,
                              float* __restrict__ attn_out)
{
  __shared__ __align__(16) unsigned int xl[4][128*36];
  __shared__ float ssh[4][16];
  __shared__ float rsh[4][16];

  const int b   = blockIdx.x / NBLK;
  const int blk = blockIdx.x - b*NBLK;
  const int tid = threadIdx.x;
  const int w = tid >> 6;
  const int l = tid & 63;
  const int c = l & 15;
  const int g = l >> 4;

  bf16x8 ufrag[8];
  {
    const bf16x8* up = reinterpret_cast<const bf16x8*>(u_buf + (size_t)(b*KS + c)*DD);
    #pragma unroll
    for (int kk = 0; kk < 8; ++kk) ufrag[kk] = up[4*kk + g];
  }
  const float su_c = su_buf[b*KS + c];
  const float cb_c = cb_buf[b*KS + c];

  float4v Pacc[16];
  #pragma unroll
  for (int t = 0; t < 16; ++t) Pacc[t] = (float4v){0.f,0.f,0.f,0.f};
  float S_acc = 0.f, R_acc = 0.f;

  unsigned int* myxl = xl[w];
  const int rbase = 8*(c>>2) + (c&3);   // n_local = rbase + 4*tp

  for (int pass = 0; pass < 4; ++pass) {
    const int n0 = blk*(NTOK/NBLK) + pass*128 + w*32;
    float4v Ct[2];
    float m_t[2], rs_t[2];

    if constexpr (MODE == 1) {
      bf16x8 xr0[8], xr1[8];
      float2 st0, st1;
      {
        const size_t row0 = (size_t)b*NTOK + (size_t)(n0 + rbase);
        const size_t row1 = row0 + 4;
        const bf16x8* p0v = reinterpret_cast<const bf16x8*>(xb + row0*FEATN);
        const bf16x8* p1v = reinterpret_cast<const bf16x8*>(xb + row1*FEATN);
        #pragma unroll
        for (int kk = 0; kk < 8; ++kk) { xr0[kk] = p0v[4*kk + g]; xr1[kk] = p1v[4*kk + g]; }
        st0 = *reinterpret_cast<const float2*>(stats + row0*2);
        st1 = *reinterpret_cast<const float2*>(stats + row1*2);
      }
      #pragma unroll
      for (int tp = 0; tp < 2; ++tp) {
        const int nloc = rbase + 4*tp;
        float4v Cacc = (float4v){0.f,0.f,0.f,0.f};
        #pragma unroll
        for (int kk = 0; kk < 8; ++kk) {
          const bf16x8 af = tp ? xr1[kk] : xr0[kk];
          const uint4v ad = __builtin_bit_cast(uint4v, af);
          const int pb = (16*kk + 4*g)*36 + nloc;
          myxl[pb      ] = ad[0];
          myxl[pb + 36 ] = ad[1];
          myxl[pb + 72 ] = ad[2];
          myxl[pb + 108] = ad[3];
          Cacc = __builtin_amdgcn_mfma_f32_16x16x32_bf16(af, ufrag[kk], Cacc, 0, 0, 0);
        }
        m_t[tp]  = tp ? st1.x : st0.x;
        rs_t[tp] = tp ? st1.y : st0.y;
        Ct[tp]   = Cacc;
      }
    } else {
      #pragma unroll
      for (int tp = 0; tp < 2; ++tp) {
        const int nloc = rbase + 4*tp;
        const size_t row = (size_t)b*NTOK + (size_t)(n0 + nloc);
        const float* fr = feat + row*FEATN;
        float4v xf[16];
        #pragma unroll
        for (int kk = 0; kk < 8; ++kk) {
          xf[2*kk]   = *reinterpret_cast<const float4v*>(fr + 32*kk + 8*g);
          xf[2*kk+1] = *reinterpret_cast<const float4v*>(fr + 32*kk + 8*g + 4);
        }
        unsigned short* xw = xb + row*FEATN;
        float sum = 0.f, sq = 0.f;
        float4v Cacc = (float4v){0.f,0.f,0.f,0.f};
        #pragma unroll
        for (int kk = 0; kk < 8; ++kk) {
          const float4v x0 = xf[2*kk], x1 = xf[2*kk+1];
          sum += x0[0]+x0[1]+x0[2]+x0[3] + x1[0]+x1[1]+x1[2]+x1[3];
          sq  += x0[0]*x0[0]+x0[1]*x0[1]+x0[2]*x0[2]+x0[3]*x0[3]
               + x1[0]*x1[0]+x1[1]*x1[1]+x1[2]*x1[2]+x1[3]*x1[3];
          bf16x8 af;
          af[0]=(__bf16)x0[0]; af[1]=(__bf16)x0[1]; af[2]=(__bf16)x0[2]; af[3]=(__bf16)x0[3];
          af[4]=(__bf16)x1[0]; af[5]=(__bf16)x1[1]; af[6]=(__bf16)x1[2]; af[7]=(__bf16)x1[3];
          *reinterpret_cast<bf16x8*>(xw + 32*kk + 8*g) = af;
          const uint4v ad = __builtin_bit_cast(uint4v, af);
          const int pb = (16*kk + 4*g)*36 + nloc;
          myxl[pb      ] = ad[0];
          myxl[pb + 36 ] = ad[1];
          myxl[pb + 72 ] = ad[2];
          myxl[pb + 108] = ad[3];
          Cacc = __builtin_amdgcn_mfma_f32_16x16x32_bf16(af, ufrag[kk], Cacc, 0, 0, 0);
        }
        sum += __shfl_xor(sum,16); sum += __shfl_xor(sum,32);
        sq  += __shfl_xor(sq ,16); sq  += __shfl_xor(sq ,32);
        const float mean = sum * (1.f/FEATN);
        const float var  = sq  * (1.f/FEATN) - mean*mean;
        m_t[tp]  = mean;
        rs_t[tp] = rsqrtf(var + LN_EPS);
        float2 st; st.x = m_t[tp]; st.y = rs_t[tp];
        *reinterpret_cast<float2*>(stats + row*2) = st;
        Ct[tp] = Cacc;
      }
    }

    float arr[8];
    #pragma unroll
    for (int tp = 0; tp < 2; ++tp) {
      float lv[4], rsr[4], mr[4];
      #pragma unroll
      for (int r = 0; r < 4; ++r) {
        const int src = 4*g + r;
        rsr[r] = __shfl(rs_t[tp], src);
        mr[r]  = __shfl(m_t[tp],  src);
        lv[r]  = 0.0625f * (rsr[r]*(Ct[tp][r] - mr[r]*su_c) + cb_c);
      }
      float a_[4];
      #pragma unroll
      for (int r = 0; r < 4; ++r) {
        float v = lv[r];
        v = fmaxf(v, __shfl_xor(v,1));
        v = fmaxf(v, __shfl_xor(v,2));
        v = fmaxf(v, __shfl_xor(v,4));
        v = fmaxf(v, __shfl_xor(v,8));
        const float e = __expf(lv[r] - v);
        float s = e;
        s += __shfl_xor(s,1);
        s += __shfl_xor(s,2);
        s += __shfl_xor(s,4);
        s += __shfl_xor(s,8);
        const float a = e / s;
        a_[r] = a;
        S_acc += a;
        R_acc += a * rsr[r] * mr[r];
        arr[4*tp + r] = a * rsr[r];
      }
      if (LAST) {
        float4v av = {a_[0], a_[1], a_[2], a_[3]};
        *reinterpret_cast<float4v*>(attn_out + (size_t)(b*KS + c)*NTOK + (size_t)(n0 + 8*g + 4*tp)) = av;
      }
    }
    bf16x8 afrag;
    #pragma unroll
    for (int j = 0; j < 8; ++j) afrag[j] = (__bf16)arr[j];

    #pragma unroll
    for (int t = 0; t < 16; ++t) {
      const unsigned int* rp = &myxl[(t*8 + (c>>1))*36 + 8*g];
      const uint4v q0 = *reinterpret_cast<const uint4v*>(rp);
      const uint4v q1 = *reinterpret_cast<const uint4v*>(rp + 4);
      const unsigned int sel = (c & 1) ? 0x07060302u : 0x05040100u;
      uint4v bd;
      bd[0] = __builtin_amdgcn_perm(q0[1], q0[0], sel);
      bd[1] = __builtin_amdgcn_perm(q0[3], q0[2], sel);
      bd[2] = __builtin_amdgcn_perm(q1[1], q1[0], sel);
      bd[3] = __builtin_amdgcn_perm(q1[3], q1[2], sel);
      const bf16x8 bfrag = __builtin_bit_cast(bf16x8, bd);
      Pacc[t] = __builtin_amdgcn_mfma_f32_16x16x32_bf16(afrag, bfrag, Pacc[t], 0, 0, 0);
    }
  }

  S_acc += __shfl_xor(S_acc,16); S_acc += __shfl_xor(S_acc,32);
  R_acc += __shfl_xor(R_acc,16); R_acc += __shfl_xor(R_acc,32);
  if (g == 0) { ssh[w][c] = S_acc; rsh[w][c] = R_acc; }

  float* pf = reinterpret_cast<float*>(myxl);
  #pragma unroll
  for (int t = 0; t < 16; ++t) {
    #pragma unroll
    for (int r = 0; r < 4; ++r) pf[(4*g + r)*256 + t*16 + c] = Pacc[t][r];
  }
  __syncthreads();
  {
    float* outp = P_part + (size_t)blockIdx.x * (KS*DD);
    const float* p0 = reinterpret_cast<const float*>(&xl[0][0]);
    const float* p1 = p0 + 4608;
    const float* p2 = p0 + 9216;
    const float* p3 = p0 + 13824;
    for (int i = tid; i < KS*DD; i += 256) outp[i] = p0[i]+p1[i]+p2[i]+p3[i];
    if (tid < KS) {
      S_part[blockIdx.x*KS + tid] = ssh[0][tid]+ssh[1][tid]+ssh[2][tid]+ssh[3][tid];
      R_part[blockIdx.x*KS + tid] = rsh[0][tid]+rsh[1][tid]+rsh[2][tid]+rsh[3][tid];
    }
  }
}

// ---------------------------------------------------------------- fused slot update, one slot/block
// grid = BB*KS = 256 blocks, 256 threads. K-split over 4 waves; LDS partial combine.
// Arena regions are STRICTLY non-overlapping (floats):
//   Pp[0..6144) | Hsh[6144..6400) | Tsh[6400..6656) | Ush[6656..6912)
//   Gish[6912..7680) | Ghsh[7680..8448) | Hpsh[8448..8704) | Ysh[8704..8960)
//   Hidsh[8960..9984)                                   total 9984 f = 39936 B
template<int LAST>
__global__ void fusedB_kernel(const float* __restrict__ P_part, const float* __restrict__ S_part,
                              const float* __restrict__ R_part, const float* __restrict__ slots_in,
                              const float* __restrict__ g_f, const float* __restrict__ b_f,
                              const unsigned short* __restrict__ Wv_t,
                              const unsigned short* __restrict__ wih_t,
                              const unsigned short* __restrict__ whh_t,
                              const float* __restrict__ b_ih, const float* __restrict__ b_hh,
                              const float* __restrict__ g_m, const float* __restrict__ b_m,
                              const unsigned short* __restrict__ W1_t, const float* __restrict__ b1,
                              const unsigned short* __restrict__ W2_t, const float* __restrict__ b2v,
                              float* __restrict__ slots_next, float* __restrict__ out_slots)
{
  const int b = blockIdx.x >> 4, k = blockIdx.x & 15;
  const int tid = threadIdx.x;
  const int w = tid >> 6, L = tid & 63;

  __shared__ __align__(16) float arena[9984];
  __shared__ float SRsh[2];
  __shared__ float redsh[8];

  float* Pp    = arena;
  float* Hsh   = arena + 6144;
  float* Tsh   = arena + 6400;
  float* Ush   = arena + 6656;
  float* Gish  = arena + 6912;
  float* Ghsh  = arena + 7680;
  float* Hpsh  = arena + 8448;
  float* Ysh   = arena + 8704;
  float* Hidsh = arena + 8960;

  // ---- slots_in load + S/R reduce
  Hsh[tid] = slots_in[(size_t)(b*KS + k)*DD + tid];
  if (tid < 64) {
    const int p = tid & 31;
    const float* sp = (tid < 32) ? S_part : R_part;
    float v = sp[(b*NBLK + p)*KS + k];
    v += __shfl_xor(v, 1); v += __shfl_xor(v, 2); v += __shfl_xor(v, 4);
    v += __shfl_xor(v, 8); v += __shfl_xor(v, 16);
    if (p == 0) SRsh[tid >> 5] = v;
  }
  __syncthreads();

  // ---- T[d] = (g_f*(P - R) + S*b_f)/(S+1)
  {
    const float S = SRsh[0], R = SRsh[1];
    const float inv = 1.f / (S + 1.f);
    const float* pb = P_part + (size_t)(b*NBLK)*KS*DD + (size_t)k*DD + tid;
    float p0 = 0.f, p1 = 0.f, p2 = 0.f, p3 = 0.f;
    #pragma unroll
    for (int p = 0; p < NBLK; p += 4) {
      p0 += pb[(size_t)(p+0)*KS*DD];
      p1 += pb[(size_t)(p+1)*KS*DD];
      p2 += pb[(size_t)(p+2)*KS*DD];
      p3 += pb[(size_t)(p+3)*KS*DD];
    }
    const float P = (p0 + p1) + (p2 + p3);
    Tsh[tid] = (g_f[tid]*(P - R) + S*b_f[tid]) * inv;
  }
  __syncthreads();

  // ---- upd = T @ Wv^T  (K-split over waves, 4 cols/thread)
  {
    const int c0 = 4*L;
    float a0 = 0.f, a1 = 0.f, a2 = 0.f, a3 = 0.f;
    for (int cc = w*64; cc < w*64+64; ++cc) {
      const float x = Tsh[cc];
      const uint2v wr = *reinterpret_cast<const uint2v*>(Wv_t + (size_t)cc*DD + c0);
      a0 += x*bflo(wr[0]); a1 += x*bfhi(wr[0]);
      a2 += x*bflo(wr[1]); a3 += x*bfhi(wr[1]);
    }
    float4v av = {a0, a1, a2, a3};
    *reinterpret_cast<float4v*>(Pp + w*256 + c0) = av;
  }
  __syncthreads();
  Ush[tid] = Pp[tid] + Pp[256+tid] + Pp[512+tid] + Pp[768+tid];
  __syncthreads();

  // ---- gi = upd@w_ih^T, gh = slots@w_hh^T (768 cols each; 12+12 cols/thread)
  {
    const int c0 = 4*L;
    float ai[3][4] = {}, ah[3][4] = {};
    for (int cc = w*64; cc < w*64+64; ++cc) {
      const float xi = Ush[cc], xh = Hsh[cc];
      #pragma unroll
      for (int c = 0; c < 3; ++c) {
        const uint2v wi = *reinterpret_cast<const uint2v*>(wih_t + (size_t)cc*768 + c0 + 256*c);
        const uint2v wh = *reinterpret_cast<const uint2v*>(whh_t + (size_t)cc*768 + c0 + 256*c);
        ai[c][0] += xi*bflo(wi[0]); ai[c][1] += xi*bfhi(wi[0]);
        ai[c][2] += xi*bflo(wi[1]); ai[c][3] += xi*bfhi(wi[1]);
        ah[c][0] += xh*bflo(wh[0]); ah[c][1] += xh*bfhi(wh[0]);
        ah[c][2] += xh*bflo(wh[1]); ah[c][3] += xh*bfhi(wh[1]);
      }
    }
    #pragma unroll
    for (int c = 0; c < 3; ++c) {
      *reinterpret_cast<float4v*>(Pp + w*768 + 256*c + c0)        = *reinterpret_cast<const float4v*>(ai[c]);
      *reinterpret_cast<float4v*>(Pp + 3072 + w*768 + 256*c + c0) = *reinterpret_cast<const float4v*>(ah[c]);
    }
  }
  __syncthreads();
  for (int j = tid; j < 768; j += 256) {
    Gish[j] = b_ih[j] + Pp[j] + Pp[768+j] + Pp[1536+j] + Pp[2304+j];
    Ghsh[j] = b_hh[j] + Pp[3072+j] + Pp[3840+j] + Pp[4608+j] + Pp[5376+j];
  }
  __syncthreads();

  // ---- GRU combine + LN(g_m,b_m)
  {
    const int d = tid;
    const float r = sigm(Gish[d] + Ghsh[d]);
    const float z = sigm(Gish[256+d] + Ghsh[256+d]);
    const float n = tanhf(Gish[512+d] + r*Ghsh[512+d]);
    const float hp = (1.f - z)*n + z*Hsh[d];
    Hpsh[d] = hp;
    float s = hp;
    #pragma unroll
    for (int m = 1; m < 64; m <<= 1) s += __shfl_xor(s, m);
    if (L == 0) redsh[w] = s;
    __syncthreads();
    const float mean = (redsh[0]+redsh[1]+redsh[2]+redsh[3]) * (1.f/DD);
    const float dv = hp - mean;
    float s2 = dv*dv;
    #pragma unroll
    for (int m = 1; m < 64; m <<= 1) s2 += __shfl_xor(s2, m);
    if (L == 0) redsh[4+w] = s2;
    __syncthreads();
    const float var = (redsh[4]+redsh[5]+redsh[6]+redsh[7]) * (1.f/DD);
    Ysh[d] = dv * rsqrtf(var + LN_EPS) * g_m[d] + b_m[d];
  }
  __syncthreads();

  // ---- MLP1: hid = relu(y2 @ W1^T + b1), 1024 cols (16 cols/thread)
  {
    const int c0 = 4*L;
    float a[4][4] = {};
    for (int cc = w*64; cc < w*64+64; ++cc) {
      const float x = Ysh[cc];
      #pragma unroll
      for (int c = 0; c < 4; ++c) {
        const uint2v wr = *reinterpret_cast<const uint2v*>(W1_t + (size_t)cc*1024 + c0 + 256*c);
        a[c][0] += x*bflo(wr[0]); a[c][1] += x*bfhi(wr[0]);
        a[c][2] += x*bflo(wr[1]); a[c][3] += x*bfhi(wr[1]);
      }
    }
    #pragma unroll
    for (int c = 0; c < 4; ++c)
      *reinterpret_cast<float4v*>(Pp + w*1024 + 256*c + c0) = *reinterpret_cast<const float4v*>(a[c]);
  }
  __syncthreads();
  for (int j = tid; j < 1024; j += 256)
    Hidsh[j] = fmaxf(b1[j] + Pp[j] + Pp[1024+j] + Pp[2048+j] + Pp[3072+j], 0.f);
  __syncthreads();

  // ---- MLP2: o = hid @ W2^T + b2 + hp   (K=1024 split: 256/wave)
  {
    const int c0 = 4*L;
    float a0 = 0.f, a1 = 0.f, a2 = 0.f, a3 = 0.f;
    for (int cc = w*256; cc < w*256+256; ++cc) {
      const float x = Hidsh[cc];
      const uint2v wr = *reinterpret_cast<const uint2v*>(W2_t + (size_t)cc*DD + c0);
      a0 += x*bflo(wr[0]); a1 += x*bfhi(wr[0]);
      a2 += x*bflo(wr[1]); a3 += x*bfhi(wr[1]);
    }
    float4v av = {a0, a1, a2, a3};
    *reinterpret_cast<float4v*>(Pp + w*256 + c0) = av;
  }
  __syncthreads();
  {
    const int d = tid;
    const float v = b2v[d] + Pp[d] + Pp[256+d] + Pp[512+d] + Pp[768+d] + Hpsh[d];
    slots_next[(size_t)(b*KS + k)*DD + d] = v;
    if (LAST) out_slots[(size_t)(b*KS + k)*DD + d] = v;
  }
}

// ---------------------------------------------------------------- host
extern "C" void kernel_launch(void* const* d_in, const int* in_sizes, int n_in,
                              void* d_out, int out_size, void* d_ws, size_t ws_size,
                              hipStream_t stream)
{
  const float* features   = (const float*)d_in[0];
  const float* slots_init = (const float*)d_in[1];
  const float* g_f = (const float*)d_in[2];
  const float* b_f = (const float*)d_in[3];
  const float* g_s = (const float*)d_in[4];
  const float* b_s = (const float*)d_in[5];
  const float* g_m = (const float*)d_in[6];
  const float* b_m = (const float*)d_in[7];
  const float* Wq  = (const float*)d_in[8];
  const float* Wk  = (const float*)d_in[9];
  const float* Wv  = (const float*)d_in[10];
  const float* w_ih = (const float*)d_in[11];
  const float* w_hh = (const float*)d_in[12];
  const float* b_ih = (const float*)d_in[13];
  const float* b_hh = (const float*)d_in[14];
  const float* W1  = (const float*)d_in[15];
  const float* b1  = (const float*)d_in[16];
  const float* W2  = (const float*)d_in[17];
  const float* b2  = (const float*)d_in[18];

  float* out_slots = (float*)d_out;
  float* out_attn  = out_slots + (size_t)BB*KS*DD;

  char* ws = (char*)d_ws;
  size_t off = 0;
  auto alloc = [&](size_t bytes) -> void* {
    void* p = ws + off;
    off += (bytes + 255) & ~(size_t)255;
    return p;
  };
  unsigned short* u_buf  = (unsigned short*)alloc((size_t)BB*KS*DD*2);
  float*          su_buf = (float*)alloc((size_t)BB*KS*4);
  float*          cb_buf = (float*)alloc((size_t)BB*KS*4);
  float*          P_part = (float*)alloc((size_t)BB*NBLK*KS*DD*4);
  float*          S_part = (float*)alloc((size_t)BB*NBLK*KS*4);
  float*          R_part = (float*)alloc((size_t)BB*NBLK*KS*4);
  float*          slots_ws = (float*)alloc((size_t)BB*KS*DD*4);
  unsigned short* Wv_t  = (unsigned short*)alloc((size_t)256*256*2);
  unsigned short* wih_t = (unsigned short*)alloc((size_t)256*768*2);
  unsigned short* whh_t = (unsigned short*)alloc((size_t)256*768*2);
  unsigned short* W1_t  = (unsigned short*)alloc((size_t)256*1024*2);
  unsigned short* W2_t  = (unsigned short*)alloc((size_t)1024*256*2);
  unsigned short* Wq_t  = (unsigned short*)alloc((size_t)256*256*2);
  unsigned short* Wk_b  = (unsigned short*)alloc((size_t)256*256*2);
  float*          stats = (float*)alloc((size_t)BB*NTOK*2*4);
  unsigned short* xb    = (unsigned short*)alloc((size_t)BB*NTOK*FEATN*2);
  (void)in_sizes; (void)n_in; (void)out_size; (void)ws_size;

  prep_w_kernel<<<272, 256, 0, stream>>>(Wv, w_ih, w_hh, W1, W2, Wq, Wk,
                                         Wv_t, wih_t, whh_t, W1_t, W2_t, Wq_t, Wk_b);
  k0_kernel<<<BB*4, 256, 0, stream>>>(slots_init, g_s, b_s, Wq_t, Wk_b, g_f, b_f,
                                      u_buf, su_buf, cb_buf);

  // iter 0
  phaseA_kernel<0,0><<<BB*NBLK, 256, 0, stream>>>(features, xb, stats, u_buf, su_buf, cb_buf,
                                                  P_part, S_part, R_part, out_attn);
  fusedB_kernel<0><<<BB*KS, 256, 0, stream>>>(P_part, S_part, R_part, slots_init, g_f, b_f,
                                              Wv_t, wih_t, whh_t, b_ih, b_hh, g_m, b_m,
                                              W1_t, b1, W2_t, b2, slots_ws, out_slots);
  k0_kernel<<<BB*4, 256, 0, stream>>>(slots_ws, g_s, b_s, Wq_t, Wk_b, g_f, b_f,
                                      u_buf, su_buf, cb_buf);
  // iter 1
  phaseA_kernel<1,0><<<BB*NBLK, 256, 0, stream>>>(features, xb, stats, u_buf, su_buf, cb_buf,
                                                  P_part, S_part, R_part, out_attn);
  fusedB_kernel<0><<<BB*KS, 256, 0, stream>>>(P_part, S_part, R_part, slots_ws, g_f, b_f,
                                              Wv_t, wih_t, whh_t, b_ih, b_hh, g_m, b_m,
                                              W1_t, b1, W2_t, b2, slots_ws, out_slots);
  k0_kernel<<<BB*4, 256, 0, stream>>>(slots_ws, g_s, b_s, Wq_t, Wk_b, g_f, b_f,
                                      u_buf, su_buf, cb_buf);
  // iter 2
  phaseA_kernel<1,1><<<BB*NBLK, 256, 0, stream>>>(features, xb, stats, u_buf, su_buf, cb_buf,
                                                  P_part, S_part, R_part, out_attn);
  fusedB_kernel<1><<<BB*KS, 256, 0, stream>>>(P_part, S_part, R_part, slots_ws, g_f, b_f,
                                              Wv_t, wih_t, whh_t, b_ih, b_hh, g_m, b_m,
                                              W1_t, b1, W2_t, b2, slots_ws, out_slots);
}

// Round 8
// 389.998 us; speedup vs baseline: 1.7360x; 1.0441x over previous
//
// SlotAttention fused forward for MI355X (gfx950) — round 8.
// r8 = r7 with the per-iteration k0 (LN->q->u tail) fused INTO fusedB:
// the tail is per-slot independent, and fusedB ends with the new slot value in
// LDS, so <NEXT> appends LN(g_s,b_s) + two K-split GEMVs (q=y@Wq^T via Wq_t,
// qk=q@Wk via Wk_b) + u/su/cb writes. Removes 3 k0 dispatches + 2 slot
// round-trips. k0 runs once on slots_init. phaseA unchanged (r6/r7-proven).
#include <hip/hip_runtime.h>
#include <cstdint>
#include <cstddef>

#define BB    16
#define NTOK  16384
#define KS    16
#define DD    256
#define FEATN 256
#define NBLK  32
#define LN_EPS 1e-5f

typedef float        float4v __attribute__((ext_vector_type(4)));
typedef unsigned int uint4v  __attribute__((ext_vector_type(4)));
typedef unsigned int uint2v  __attribute__((ext_vector_type(2)));
typedef __bf16       bf16x8  __attribute__((ext_vector_type(8)));

__device__ __forceinline__ float bflo(unsigned u){ return __builtin_bit_cast(float, u << 16); }
__device__ __forceinline__ float bfhi(unsigned u){ return __builtin_bit_cast(float, u & 0xffff0000u); }
__device__ __forceinline__ unsigned short f2bf(float v){ __bf16 b = (__bf16)v; return __builtin_bit_cast(unsigned short, b); }
__device__ __forceinline__ float sigm(float x){ return 1.f/(1.f + __expf(-x)); }

// ---------------------------------------------------------------- weight prep
__global__ void prep_w_kernel(const float* __restrict__ Wv, const float* __restrict__ w_ih,
                              const float* __restrict__ w_hh, const float* __restrict__ W1,
                              const float* __restrict__ W2, const float* __restrict__ Wq,
                              const float* __restrict__ Wk,
                              unsigned short* __restrict__ Wv_t, unsigned short* __restrict__ wih_t,
                              unsigned short* __restrict__ whh_t, unsigned short* __restrict__ W1_t,
                              unsigned short* __restrict__ W2_t, unsigned short* __restrict__ Wq_t,
                              unsigned short* __restrict__ Wk_b)
{
  __shared__ float tile[64][65];
  const int t = blockIdx.x, tid = threadIdx.x;
  const float* src; unsigned short* dst; int R, C, base;
  if      (t < 16)  { src = Wv;   dst = Wv_t;  R = 256;  C = 256;  base = 0;   }
  else if (t < 64)  { src = w_ih; dst = wih_t; R = 768;  C = 256;  base = 16;  }
  else if (t < 112) { src = w_hh; dst = whh_t; R = 768;  C = 256;  base = 64;  }
  else if (t < 176) { src = W1;   dst = W1_t;  R = 1024; C = 256;  base = 112; }
  else if (t < 240) { src = W2;   dst = W2_t;  R = 256;  C = 1024; base = 176; }
  else if (t < 256) { src = Wq;   dst = Wq_t;  R = 256;  C = 256;  base = 240; }
  else {
    const int t2 = t - 256;
    for (int i = tid; i < 4096; i += 256) {
      const int idx = t2*4096 + i;
      Wk_b[idx] = f2bf(Wk[idx]);
    }
    return;
  }
  const int tt = t - base;
  const int tiles_r = R >> 6;
  const int r0 = (tt % tiles_r) * 64, c0 = (tt / tiles_r) * 64;
  const int j = tid & 63, i0 = (tid >> 6) * 16;
  for (int s = 0; s < 16; ++s)
    tile[i0 + s][j] = src[(size_t)(r0 + i0 + s)*C + c0 + j];
  __syncthreads();
  for (int s = 0; s < 16; ++s) {
    const int i = i0 + s;
    dst[(size_t)(c0 + i)*R + r0 + j] = f2bf(tile[j][i]);
  }
}

// ---------------------------------------------------------------- LN->q->u/su/cb tail (k0 only)
__device__ __forceinline__ void lnqu_tail_p(
    const float* Vs, float* Ys, float* Qs, float* Pp, float* SUb, float* CBb,
    const float* __restrict__ g_s, const float* __restrict__ b_s,
    const unsigned short* __restrict__ Wq_t, const unsigned short* __restrict__ Wk_b,
    const float* __restrict__ g_f, const float* __restrict__ b_f,
    unsigned short* __restrict__ u_buf, float* __restrict__ su_buf, float* __restrict__ cb_buf,
    int b, int k0, int tid)
{
  const int w = tid >> 6, L = tid & 63;
  {
    const float v0 = Vs[w*256+L], v1 = Vs[w*256+64+L], v2 = Vs[w*256+128+L], v3 = Vs[w*256+192+L];
    float s = v0+v1+v2+v3;
    #pragma unroll
    for (int m = 1; m < 64; m <<= 1) s += __shfl_xor(s, m);
    const float mean = s * (1.f/DD);
    const float d0 = v0-mean, d1 = v1-mean, d2 = v2-mean, d3 = v3-mean;
    float s2 = d0*d0 + d1*d1 + d2*d2 + d3*d3;
    #pragma unroll
    for (int m = 1; m < 64; m <<= 1) s2 += __shfl_xor(s2, m);
    const float rs = rsqrtf(s2 * (1.f/DD) + LN_EPS);
    Ys[L*4+w]       = d0*rs*g_s[L]      + b_s[L];
    Ys[(64+L)*4+w]  = d1*rs*g_s[64+L]   + b_s[64+L];
    Ys[(128+L)*4+w] = d2*rs*g_s[128+L]  + b_s[128+L];
    Ys[(192+L)*4+w] = d3*rs*g_s[192+L]  + b_s[192+L];
  }
  __syncthreads();
  {
    float acc[4][4] = {};
    for (int cc = w*64; cc < w*64+64; ++cc) {
      const float4v xv = *reinterpret_cast<const float4v*>(Ys + cc*4);
      const uint2v wr = *reinterpret_cast<const uint2v*>(Wq_t + (size_t)cc*DD + 4*L);
      const float w0 = bflo(wr[0]), w1 = bfhi(wr[0]), w2 = bflo(wr[1]), w3 = bfhi(wr[1]);
      #pragma unroll
      for (int s = 0; s < 4; ++s) {
        acc[s][0] += xv[s]*w0; acc[s][1] += xv[s]*w1;
        acc[s][2] += xv[s]*w2; acc[s][3] += xv[s]*w3;
      }
    }
    #pragma unroll
    for (int s = 0; s < 4; ++s)
      *reinterpret_cast<float4v*>(Pp + (w*4+s)*256 + 4*L) = *reinterpret_cast<const float4v*>(acc[s]);
  }
  __syncthreads();
  for (int i = tid; i < 4*DD; i += 256) {
    const int kk = i >> 8, d = i & 255;
    Qs[d*4+kk] = Pp[(0*4+kk)*256+d] + Pp[(1*4+kk)*256+d] + Pp[(2*4+kk)*256+d] + Pp[(3*4+kk)*256+d];
  }
  __syncthreads();
  {
    float acc[4][4] = {};
    for (int d = w*64; d < w*64+64; ++d) {
      const float4v xv = *reinterpret_cast<const float4v*>(Qs + d*4);
      const uint2v wr = *reinterpret_cast<const uint2v*>(Wk_b + (size_t)d*DD + 4*L);
      const float w0 = bflo(wr[0]), w1 = bfhi(wr[0]), w2 = bflo(wr[1]), w3 = bfhi(wr[1]);
      #pragma unroll
      for (int s = 0; s < 4; ++s) {
        acc[s][0] += xv[s]*w0; acc[s][1] += xv[s]*w1;
        acc[s][2] += xv[s]*w2; acc[s][3] += xv[s]*w3;
      }
    }
    #pragma unroll
    for (int s = 0; s < 4; ++s)
      *reinterpret_cast<float4v*>(Pp + (w*4+s)*256 + 4*L) = *reinterpret_cast<const float4v*>(acc[s]);
  }
  __syncthreads();
  for (int i = tid; i < 4*DD; i += 256) {
    const int kk = i >> 8, cc = i & 255;
    const float qk = Pp[(0*4+kk)*256+cc] + Pp[(1*4+kk)*256+cc] + Pp[(2*4+kk)*256+cc] + Pp[(3*4+kk)*256+cc];
    const float uv = qk * g_f[cc];
    u_buf[(size_t)(b*KS + k0 + kk)*DD + cc] = f2bf(uv);
    SUb[kk*256+cc] = uv;
    CBb[kk*256+cc] = qk * b_f[cc];
  }
  __syncthreads();
  {
    float s  = SUb[w*256+L] + SUb[w*256+64+L] + SUb[w*256+128+L] + SUb[w*256+192+L];
    float cv = CBb[w*256+L] + CBb[w*256+64+L] + CBb[w*256+128+L] + CBb[w*256+192+L];
    #pragma unroll
    for (int m = 1; m < 64; m <<= 1) { s += __shfl_xor(s, m); cv += __shfl_xor(cv, m); }
    if (L == 0) { su_buf[b*KS + k0 + w] = s; cb_buf[b*KS + k0 + w] = cv; }
  }
}

// ---------------------------------------------------------------- K0 (initial u only)
__global__ void k0_kernel(const float* __restrict__ slots_init,
                          const float* __restrict__ g_s, const float* __restrict__ b_s,
                          const unsigned short* __restrict__ Wq_t, const unsigned short* __restrict__ Wk_b,
                          const float* __restrict__ g_f, const float* __restrict__ b_f,
                          unsigned short* __restrict__ u_buf, float* __restrict__ su_buf,
                          float* __restrict__ cb_buf)
{
  const int b = blockIdx.x >> 2, k0 = (blockIdx.x & 3) * 4;
  const int tid = threadIdx.x;
  __shared__ __align__(16) float Vs[4*DD];
  __shared__ __align__(16) float Ys[DD*4];
  __shared__ __align__(16) float Qs[DD*4];
  __shared__ __align__(16) float Pp[4*4*DD];
  __shared__ __align__(16) float SUb[4*DD];
  __shared__ __align__(16) float CBb[4*DD];
  for (int i = tid; i < 4*DD; i += 256)
    Vs[i] = slots_init[(size_t)(b*KS + k0)*DD + i];
  __syncthreads();
  lnqu_tail_p(Vs, Ys, Qs, Pp, SUb, CBb, g_s, b_s, Wq_t, Wk_b, g_f, b_f,
              u_buf, su_buf, cb_buf, b, k0, tid);
}

// ---------------------------------------------------------------- phase A (unchanged, r6/r7-passing)
template<int MODE, int LAST>
__launch_bounds__(256, 2)
__global__ void phaseA_kernel(const float* __restrict__ feat,
                              unsigned short* __restrict__ xb, float* __restrict__ stats,
                              const unsigned short* __restrict__ u_buf,
                              const float* __restrict__ su_buf,
                              const float* __restrict__ cb_buf,
                              float* __restrict__ P_part,
                              float* __restrict__ S_part,
                              float* __restrict__ R_part,
                              float* __restrict__ attn_out)
{
  __shared__ __align__(16) unsigned int xl[4][128*36];
  __shared__ float ssh[4][16];
  __shared__ float rsh[4][16];

  const int b   = blockIdx.x / NBLK;
  const int blk = blockIdx.x - b*NBLK;
  const int tid = threadIdx.x;
  const int w = tid >> 6;
  const int l = tid & 63;
  const int c = l & 15;
  const int g = l >> 4;

  bf16x8 ufrag[8];
  {
    const bf16x8* up = reinterpret_cast<const bf16x8*>(u_buf + (size_t)(b*KS + c)*DD);
    #pragma unroll
    for (int kk = 0; kk < 8; ++kk) ufrag[kk] = up[4*kk + g];
  }
  const float su_c = su_buf[b*KS + c];
  const float cb_c = cb_buf[b*KS + c];

  float4v Pacc[16];
  #pragma unroll
  for (int t = 0; t < 16; ++t) Pacc[t] = (float4v){0.f,0.f,0.f,0.f};
  float S_acc = 0.f, R_acc = 0.f;

  unsigned int* myxl = xl[w];
  const int rbase = 8*(c>>2) + (c&3);   // n_local = rbase + 4*tp

  for (int pass = 0; pass < 4; ++pass) {
    const int n0 = blk*(NTOK/NBLK) + pass*128 + w*32;
    float4v Ct[2];
    float m_t[2], rs_t[2];

    if constexpr (MODE == 1) {
      bf16x8 xr0[8], xr1[8];
      float2 st0, st1;
      {
        const size_t row0 = (size_t)b*NTOK + (size_t)(n0 + rbase);
        const size_t row1 = row0 + 4;
        const bf16x8* p0v = reinterpret_cast<const bf16x8*>(xb + row0*FEATN);
        const bf16x8* p1v = reinterpret_cast<const bf16x8*>(xb + row1*FEATN);
        #pragma unroll
        for (int kk = 0; kk < 8; ++kk) { xr0[kk] = p0v[4*kk + g]; xr1[kk] = p1v[4*kk + g]; }
        st0 = *reinterpret_cast<const float2*>(stats + row0*2);
        st1 = *reinterpret_cast<const float2*>(stats + row1*2);
      }
      #pragma unroll
      for (int tp = 0; tp < 2; ++tp) {
        const int nloc = rbase + 4*tp;
        float4v Cacc = (float4v){0.f,0.f,0.f,0.f};
        #pragma unroll
        for (int kk = 0; kk < 8; ++kk) {
          const bf16x8 af = tp ? xr1[kk] : xr0[kk];
          const uint4v ad = __builtin_bit_cast(uint4v, af);
          const int pb = (16*kk + 4*g)*36 + nloc;
          myxl[pb      ] = ad[0];
          myxl[pb + 36 ] = ad[1];
          myxl[pb + 72 ] = ad[2];
          myxl[pb + 108] = ad[3];
          Cacc = __builtin_amdgcn_mfma_f32_16x16x32_bf16(af, ufrag[kk], Cacc, 0, 0, 0);
        }
        m_t[tp]  = tp ? st1.x : st0.x;
        rs_t[tp] = tp ? st1.y : st0.y;
        Ct[tp]   = Cacc;
      }
    } else {
      #pragma unroll
      for (int tp = 0; tp < 2; ++tp) {
        const int nloc = rbase + 4*tp;
        const size_t row = (size_t)b*NTOK + (size_t)(n0 + nloc);
        const float* fr = feat + row*FEATN;
        float4v xf[16];
        #pragma unroll
        for (int kk = 0; kk < 8; ++kk) {
          xf[2*kk]   = *reinterpret_cast<const float4v*>(fr + 32*kk + 8*g);
          xf[2*kk+1] = *reinterpret_cast<const float4v*>(fr + 32*kk + 8*g + 4);
        }
        unsigned short* xw = xb + row*FEATN;
        float sum = 0.f, sq = 0.f;
        float4v Cacc = (float4v){0.f,0.f,0.f,0.f};
        #pragma unroll
        for (int kk = 0; kk < 8; ++kk) {
          const float4v x0 = xf[2*kk], x1 = xf[2*kk+1];
          sum += x0[0]+x0[1]+x0[2]+x0[3] + x1[0]+x1[1]+x1[2]+x1[3];
          sq  += x0[0]*x0[0]+x0[1]*x0[1]+x0[2]*x0[2]+x0[3]*x0[3]
               + x1[0]*x1[0]+x1[1]*x1[1]+x1[2]*x1[2]+x1[3]*x1[3];
          bf16x8 af;
          af[0]=(__bf16)x0[0]; af[1]=(__bf16)x0[1]; af[2]=(__bf16)x0[2]; af[3]=(__bf16)x0[3];
          af[4]=(__bf16)x1[0]; af[5]=(__bf16)x1[1]; af[6]=(__bf16)x1[2]; af[7]=(__bf16)x1[3];
          *reinterpret_cast<bf16x8*>(xw + 32*kk + 8*g) = af;
          const uint4v ad = __builtin_bit_cast(uint4v, af);
          const int pb = (16*kk + 4*g)*36 + nloc;
          myxl[pb      ] = ad[0];
          myxl[pb + 36 ] = ad[1];
          myxl[pb + 72 ] = ad[2];
          myxl[pb + 108] = ad[3];
          Cacc = __builtin_amdgcn_mfma_f32_16x16x32_bf16(af, ufrag[kk], Cacc, 0, 0, 0);
        }
        sum += __shfl_xor(sum,16); sum += __shfl_xor(sum,32);
        sq  += __shfl_xor(sq ,16); sq  += __shfl_xor(sq ,32);
        const float mean = sum * (1.f/FEATN);
        const float var  = sq  * (1.f/FEATN) - mean*mean;
        m_t[tp]  = mean;
        rs_t[tp] = rsqrtf(var + LN_EPS);
        float2 st; st.x = m_t[tp]; st.y = rs_t[tp];
        *reinterpret_cast<float2*>(stats + row*2) = st;
        Ct[tp] = Cacc;
      }
    }

    float arr[8];
    #pragma unroll
    for (int tp = 0; tp < 2; ++tp) {
      float lv[4], rsr[4], mr[4];
      #pragma unroll
      for (int r = 0; r < 4; ++r) {
        const int src = 4*g + r;
        rsr[r] = __shfl(rs_t[tp], src);
        mr[r]  = __shfl(m_t[tp],  src);
        lv[r]  = 0.0625f * (rsr[r]*(Ct[tp][r] - mr[r]*su_c) + cb_c);
      }
      float a_[4];
      #pragma unroll
      for (int r = 0; r < 4; ++r) {
        float v = lv[r];
        v = fmaxf(v, __shfl_xor(v,1));
        v = fmaxf(v, __shfl_xor(v,2));
        v = fmaxf(v, __shfl_xor(v,4));
        v = fmaxf(v, __shfl_xor(v,8));
        const float e = __expf(lv[r] - v);
        float s = e;
        s += __shfl_xor(s,1);
        s += __shfl_xor(s,2);
        s += __shfl_xor(s,4);
        s += __shfl_xor(s,8);
        const float a = e / s;
        a_[r] = a;
        S_acc += a;
        R_acc += a * rsr[r] * mr[r];
        arr[4*tp + r] = a * rsr[r];
      }
      if (LAST) {
        float4v av = {a_[0], a_[1], a_[2], a_[3]};
        *reinterpret_cast<float4v*>(attn_out + (size_t)(b*KS + c)*NTOK + (size_t)(n0 + 8*g + 4*tp)) = av;
      }
    }
    bf16x8 afrag;
    #pragma unroll
    for (int j = 0; j < 8; ++j) afrag[j] = (__bf16)arr[j];

    #pragma unroll
    for (int t = 0; t < 16; ++t) {
      const unsigned int* rp = &myxl[(t*8 + (c>>1))*36 + 8*g];
      const uint4v q0 = *reinterpret_cast<const uint4v*>(rp);
      const uint4v q1 = *reinterpret_cast<const uint4v*>(rp + 4);
      const unsigned int sel = (c & 1) ? 0x07060302u : 0x05040100u;
      uint4v bd;
      bd[0] = __builtin_amdgcn_perm(q0[1], q0[0], sel);
      bd[1] = __builtin_amdgcn_perm(q0[3], q0[2], sel);
      bd[2] = __builtin_amdgcn_perm(q1[1], q1[0], sel);
      bd[3] = __builtin_amdgcn_perm(q1[3], q1[2], sel);
      const bf16x8 bfrag = __builtin_bit_cast(bf16x8, bd);
      Pacc[t] = __builtin_amdgcn_mfma_f32_16x16x32_bf16(afrag, bfrag, Pacc[t], 0, 0, 0);
    }
  }

  S_acc += __shfl_xor(S_acc,16); S_acc += __shfl_xor(S_acc,32);
  R_acc += __shfl_xor(R_acc,16); R_acc += __shfl_xor(R_acc,32);
  if (g == 0) { ssh[w][c] = S_acc; rsh[w][c] = R_acc; }

  float* pf = reinterpret_cast<float*>(myxl);
  #pragma unroll
  for (int t = 0; t < 16; ++t) {
    #pragma unroll
    for (int r = 0; r < 4; ++r) pf[(4*g + r)*256 + t*16 + c] = Pacc[t][r];
  }
  __syncthreads();
  {
    float* outp = P_part + (size_t)blockIdx.x * (KS*DD);
    const float* p0 = reinterpret_cast<const float*>(&xl[0][0]);
    const float* p1 = p0 + 4608;
    const float* p2 = p0 + 9216;
    const float* p3 = p0 + 13824;
    for (int i = tid; i < KS*DD; i += 256) outp[i] = p0[i]+p1[i]+p2[i]+p3[i];
    if (tid < KS) {
      S_part[blockIdx.x*KS + tid] = ssh[0][tid]+ssh[1][tid]+ssh[2][tid]+ssh[3][tid];
      R_part[blockIdx.x*KS + tid] = rsh[0][tid]+rsh[1][tid]+rsh[2][tid]+rsh[3][tid];
    }
  }
}

// ---------------------------------------------------------------- fused slot update + next-iter tail
// grid = BB*KS = 256 blocks, 256 threads, one slot each.
// Arena (floats, strictly non-overlapping):
//   Pp[0..6144) | Hsh[6144..6400) | Tsh[6400..6656) | Ush[6656..6912)
//   Gish[6912..7680) | Ghsh[7680..8448) | Hpsh[8448..8704) | Ysh[8704..8960)
//   Hidsh[8960..9984)
template<int LAST, int NEXT>
__global__ void fusedB_kernel(const float* __restrict__ P_part, const float* __restrict__ S_part,
                              const float* __restrict__ R_part, const float* __restrict__ slots_in,
                              const float* __restrict__ g_f, const float* __restrict__ b_f,
                              const unsigned short* __restrict__ Wv_t,
                              const unsigned short* __restrict__ wih_t,
                              const unsigned short* __restrict__ whh_t,
                              const float* __restrict__ b_ih, const float* __restrict__ b_hh,
                              const float* __restrict__ g_m, const float* __restrict__ b_m,
                              const unsigned short* __restrict__ W1_t, const float* __restrict__ b1,
                              const unsigned short* __restrict__ W2_t, const float* __restrict__ b2v,
                              const float* __restrict__ g_s, const float* __restrict__ b_s,
                              const unsigned short* __restrict__ Wq_t,
                              const unsigned short* __restrict__ Wk_b,
                              float* __restrict__ slots_next, float* __restrict__ out_slots,
                              unsigned short* __restrict__ u_buf, float* __restrict__ su_buf,
                              float* __restrict__ cb_buf)
{
  const int b = blockIdx.x >> 4, k = blockIdx.x & 15;
  const int tid = threadIdx.x;
  const int w = tid >> 6, L = tid & 63;

  __shared__ __align__(16) float arena[9984];
  __shared__ float SRsh[2];
  __shared__ float redsh[8];

  float* Pp    = arena;
  float* Hsh   = arena + 6144;
  float* Tsh   = arena + 6400;
  float* Ush   = arena + 6656;
  float* Gish  = arena + 6912;
  float* Ghsh  = arena + 7680;
  float* Hpsh  = arena + 8448;
  float* Ysh   = arena + 8704;
  float* Hidsh = arena + 8960;

  // ---- slots_in load + S/R reduce
  Hsh[tid] = slots_in[(size_t)(b*KS + k)*DD + tid];
  if (tid < 64) {
    const int p = tid & 31;
    const float* sp = (tid < 32) ? S_part : R_part;
    float v = sp[(b*NBLK + p)*KS + k];
    v += __shfl_xor(v, 1); v += __shfl_xor(v, 2); v += __shfl_xor(v, 4);
    v += __shfl_xor(v, 8); v += __shfl_xor(v, 16);
    if (p == 0) SRsh[tid >> 5] = v;
  }
  __syncthreads();

  // ---- T[d] = (g_f*(P - R) + S*b_f)/(S+1)
  {
    const float S = SRsh[0], R = SRsh[1];
    const float inv = 1.f / (S + 1.f);
    const float* pb = P_part + (size_t)(b*NBLK)*KS*DD + (size_t)k*DD + tid;
    float p0 = 0.f, p1 = 0.f, p2 = 0.f, p3 = 0.f;
    #pragma unroll
    for (int p = 0; p < NBLK; p += 4) {
      p0 += pb[(size_t)(p+0)*KS*DD];
      p1 += pb[(size_t)(p+1)*KS*DD];
      p2 += pb[(size_t)(p+2)*KS*DD];
      p3 += pb[(size_t)(p+3)*KS*DD];
    }
    const float P = (p0 + p1) + (p2 + p3);
    Tsh[tid] = (g_f[tid]*(P - R) + S*b_f[tid]) * inv;
  }
  __syncthreads();

  // ---- upd = T @ Wv^T
  {
    const int c0 = 4*L;
    float a0 = 0.f, a1 = 0.f, a2 = 0.f, a3 = 0.f;
    for (int cc = w*64; cc < w*64+64; ++cc) {
      const float x = Tsh[cc];
      const uint2v wr = *reinterpret_cast<const uint2v*>(Wv_t + (size_t)cc*DD + c0);
      a0 += x*bflo(wr[0]); a1 += x*bfhi(wr[0]);
      a2 += x*bflo(wr[1]); a3 += x*bfhi(wr[1]);
    }
    float4v av = {a0, a1, a2, a3};
    *reinterpret_cast<float4v*>(Pp + w*256 + c0) = av;
  }
  __syncthreads();
  Ush[tid] = Pp[tid] + Pp[256+tid] + Pp[512+tid] + Pp[768+tid];
  __syncthreads();

  // ---- gi = upd@w_ih^T, gh = slots@w_hh^T
  {
    const int c0 = 4*L;
    float ai[3][4] = {}, ah[3][4] = {};
    for (int cc = w*64; cc < w*64+64; ++cc) {
      const float xi = Ush[cc], xh = Hsh[cc];
      #pragma unroll
      for (int c = 0; c < 3; ++c) {
        const uint2v wi = *reinterpret_cast<const uint2v*>(wih_t + (size_t)cc*768 + c0 + 256*c);
        const uint2v wh = *reinterpret_cast<const uint2v*>(whh_t + (size_t)cc*768 + c0 + 256*c);
        ai[c][0] += xi*bflo(wi[0]); ai[c][1] += xi*bfhi(wi[0]);
        ai[c][2] += xi*bflo(wi[1]); ai[c][3] += xi*bfhi(wi[1]);
        ah[c][0] += xh*bflo(wh[0]); ah[c][1] += xh*bfhi(wh[0]);
        ah[c][2] += xh*bflo(wh[1]); ah[c][3] += xh*bfhi(wh[1]);
      }
    }
    #pragma unroll
    for (int c = 0; c < 3; ++c) {
      *reinterpret_cast<float4v*>(Pp + w*768 + 256*c + c0)        = *reinterpret_cast<const float4v*>(ai[c]);
      *reinterpret_cast<float4v*>(Pp + 3072 + w*768 + 256*c + c0) = *reinterpret_cast<const float4v*>(ah[c]);
    }
  }
  __syncthreads();
  for (int j = tid; j < 768; j += 256) {
    Gish[j] = b_ih[j] + Pp[j] + Pp[768+j] + Pp[1536+j] + Pp[2304+j];
    Ghsh[j] = b_hh[j] + Pp[3072+j] + Pp[3840+j] + Pp[4608+j] + Pp[5376+j];
  }
  __syncthreads();

  // ---- GRU combine + LN(g_m,b_m)
  {
    const int d = tid;
    const float r = sigm(Gish[d] + Ghsh[d]);
    const float z = sigm(Gish[256+d] + Ghsh[256+d]);
    const float n = tanhf(Gish[512+d] + r*Ghsh[512+d]);
    const float hp = (1.f - z)*n + z*Hsh[d];
    Hpsh[d] = hp;
    float s = hp;
    #pragma unroll
    for (int m = 1; m < 64; m <<= 1) s += __shfl_xor(s, m);
    if (L == 0) redsh[w] = s;
    __syncthreads();
    const float mean = (redsh[0]+redsh[1]+redsh[2]+redsh[3]) * (1.f/DD);
    const float dv = hp - mean;
    float s2 = dv*dv;
    #pragma unroll
    for (int m = 1; m < 64; m <<= 1) s2 += __shfl_xor(s2, m);
    if (L == 0) redsh[4+w] = s2;
    __syncthreads();
    const float var = (redsh[4]+redsh[5]+redsh[6]+redsh[7]) * (1.f/DD);
    Ysh[d] = dv * rsqrtf(var + LN_EPS) * g_m[d] + b_m[d];
  }
  __syncthreads();

  // ---- MLP1
  {
    const int c0 = 4*L;
    float a[4][4] = {};
    for (int cc = w*64; cc < w*64+64; ++cc) {
      const float x = Ysh[cc];
      #pragma unroll
      for (int c = 0; c < 4; ++c) {
        const uint2v wr = *reinterpret_cast<const uint2v*>(W1_t + (size_t)cc*1024 + c0 + 256*c);
        a[c][0] += x*bflo(wr[0]); a[c][1] += x*bfhi(wr[0]);
        a[c][2] += x*bflo(wr[1]); a[c][3] += x*bfhi(wr[1]);
      }
    }
    #pragma unroll
    for (int c = 0; c < 4; ++c)
      *reinterpret_cast<float4v*>(Pp + w*1024 + 256*c + c0) = *reinterpret_cast<const float4v*>(a[c]);
  }
  __syncthreads();
  for (int j = tid; j < 1024; j += 256)
    Hidsh[j] = fmaxf(b1[j] + Pp[j] + Pp[1024+j] + Pp[2048+j] + Pp[3072+j], 0.f);
  __syncthreads();

  // ---- MLP2 + residual
  {
    const int c0 = 4*L;
    float a0 = 0.f, a1 = 0.f, a2 = 0.f, a3 = 0.f;
    for (int cc = w*256; cc < w*256+256; ++cc) {
      const float x = Hidsh[cc];
      const uint2v wr = *reinterpret_cast<const uint2v*>(W2_t + (size_t)cc*DD + c0);
      a0 += x*bflo(wr[0]); a1 += x*bfhi(wr[0]);
      a2 += x*bflo(wr[1]); a3 += x*bfhi(wr[1]);
    }
    float4v av = {a0, a1, a2, a3};
    *reinterpret_cast<float4v*>(Pp + w*256 + c0) = av;
  }
  __syncthreads();
  {
    const int d = tid;
    const float v = b2v[d] + Pp[d] + Pp[256+d] + Pp[512+d] + Pp[768+d] + Hpsh[d];
    Tsh[d] = v;  // Tsh dead since Wv GEMV; reuse as new-slot storage
    slots_next[(size_t)(b*KS + k)*DD + d] = v;
    if (LAST) out_slots[(size_t)(b*KS + k)*DD + d] = v;
  }

  // ================= next-iteration LN(g_s,b_s) -> q -> u/su/cb (per-slot) =================
  if constexpr (NEXT) {
    __syncthreads();
    // LN over Tsh -> y in Ush (Ush dead since gates)
    {
      const float v = Tsh[tid];
      float s = v;
      #pragma unroll
      for (int m = 1; m < 64; m <<= 1) s += __shfl_xor(s, m);
      if (L == 0) redsh[w] = s;
      __syncthreads();
      const float mean = (redsh[0]+redsh[1]+redsh[2]+redsh[3]) * (1.f/DD);
      const float dv = v - mean;
      float s2 = dv*dv;
      #pragma unroll
      for (int m = 1; m < 64; m <<= 1) s2 += __shfl_xor(s2, m);
      if (L == 0) redsh[4+w] = s2;
      __syncthreads();
      const float var = (redsh[4]+redsh[5]+redsh[6]+redsh[7]) * (1.f/DD);
      Ush[tid] = dv * rsqrtf(var + LN_EPS) * g_s[tid] + b_s[tid];
    }
    __syncthreads();
    // q[d] = sum_c y[c] * Wq_t[c][d]   (K-split over waves)
    {
      const int c0 = 4*L;
      float a0 = 0.f, a1 = 0.f, a2 = 0.f, a3 = 0.f;
      for (int cc = w*64; cc < w*64+64; ++cc) {
        const float x = Ush[cc];
        const uint2v wr = *reinterpret_cast<const uint2v*>(Wq_t + (size_t)cc*DD + c0);
        a0 += x*bflo(wr[0]); a1 += x*bfhi(wr[0]);
        a2 += x*bflo(wr[1]); a3 += x*bfhi(wr[1]);
      }
      float4v av = {a0, a1, a2, a3};
      *reinterpret_cast<float4v*>(Pp + w*256 + c0) = av;
    }
    __syncthreads();
    Hsh[tid] = Pp[tid] + Pp[256+tid] + Pp[512+tid] + Pp[768+tid];  // q (Hsh dead since GRU)
    __syncthreads();
    // qk[c] = sum_d q[d] * Wk_b[d][c]
    {
      const int c0 = 4*L;
      float a0 = 0.f, a1 = 0.f, a2 = 0.f, a3 = 0.f;
      for (int dd = w*64; dd < w*64+64; ++dd) {
        const float x = Hsh[dd];
        const uint2v wr = *reinterpret_cast<const uint2v*>(Wk_b + (size_t)dd*DD + c0);
        a0 += x*bflo(wr[0]); a1 += x*bfhi(wr[0]);
        a2 += x*bflo(wr[1]); a3 += x*bfhi(wr[1]);
      }
      float4v av = {a0, a1, a2, a3};
      *reinterpret_cast<float4v*>(Pp + w*256 + c0) = av;
    }
    __syncthreads();
    {
      const int cidx = tid;
      const float qk = Pp[cidx] + Pp[256+cidx] + Pp[512+cidx] + Pp[768+cidx];
      const float uv = qk * g_f[cidx];
      u_buf[(size_t)(b*KS + k)*DD + cidx] = f2bf(uv);
      float s  = uv;
      float cv = qk * b_f[cidx];
      #pragma unroll
      for (int m = 1; m < 64; m <<= 1) { s += __shfl_xor(s, m); cv += __shfl_xor(cv, m); }
      if (L == 0) { redsh[w] = s; redsh[4+w] = cv; }
      __syncthreads();
      if (tid == 0) {
        su_buf[b*KS + k] = redsh[0]+redsh[1]+redsh[2]+redsh[3];
        cb_buf[b*KS + k] = redsh[4]+redsh[5]+redsh[6]+redsh[7];
      }
    }
  }
}

// ---------------------------------------------------------------- host
extern "C" void kernel_launch(void* const* d_in, const int* in_sizes, int n_in,
                              void* d_out, int out_size, void* d_ws, size_t ws_size,
                              hipStream_t stream)
{
  const float* features   = (const float*)d_in[0];
  const float* slots_init = (const float*)d_in[1];
  const float* g_f = (const float*)d_in[2];
  const float* b_f = (const float*)d_in[3];
  const float* g_s = (const float*)d_in[4];
  const float* b_s = (const float*)d_in[5];
  const float* g_m = (const float*)d_in[6];
  const float* b_m = (const float*)d_in[7];
  const float* Wq  = (const float*)d_in[8];
  const float* Wk  = (const float*)d_in[9];
  const float* Wv  = (const float*)d_in[10];
  const float* w_ih = (const float*)d_in[11];
  const float* w_hh = (const float*)d_in[12];
  const float* b_ih = (const float*)d_in[13];
  const float* b_hh = (const float*)d_in[14];
  const float* W1  = (const float*)d_in[15];
  const float* b1  = (const float*)d_in[16];
  const float* W2  = (const float*)d_in[17];
  const float* b2  = (const float*)d_in[18];

  float* out_slots = (float*)d_out;
  float* out_attn  = out_slots + (size_t)BB*KS*DD;

  char* ws = (char*)d_ws;
  size_t off = 0;
  auto alloc = [&](size_t bytes) -> void* {
    void* p = ws + off;
    off += (bytes + 255) & ~(size_t)255;
    return p;
  };
  unsigned short* u_buf  = (unsigned short*)alloc((size_t)BB*KS*DD*2);
  float*          su_buf = (float*)alloc((size_t)BB*KS*4);
  float*          cb_buf = (float*)alloc((size_t)BB*KS*4);
  float*          P_part = (float*)alloc((size_t)BB*NBLK*KS*DD*4);
  float*          S_part = (float*)alloc((size_t)BB*NBLK*KS*4);
  float*          R_part = (float*)alloc((size_t)BB*NBLK*KS*4);
  float*          slots_ws = (float*)alloc((size_t)BB*KS*DD*4);
  unsigned short* Wv_t  = (unsigned short*)alloc((size_t)256*256*2);
  unsigned short* wih_t = (unsigned short*)alloc((size_t)256*768*2);
  unsigned short* whh_t = (unsigned short*)alloc((size_t)256*768*2);
  unsigned short* W1_t  = (unsigned short*)alloc((size_t)256*1024*2);
  unsigned short* W2_t  = (unsigned short*)alloc((size_t)1024*256*2);
  unsigned short* Wq_t  = (unsigned short*)alloc((size_t)256*256*2);
  unsigned short* Wk_b  = (unsigned short*)alloc((size_t)256*256*2);
  float*          stats = (float*)alloc((size_t)BB*NTOK*2*4);
  unsigned short* xb    = (unsigned short*)alloc((size_t)BB*NTOK*FEATN*2);
  (void)in_sizes; (void)n_in; (void)out_size; (void)ws_size;

  prep_w_kernel<<<272, 256, 0, stream>>>(Wv, w_ih, w_hh, W1, W2, Wq, Wk,
                                         Wv_t, wih_t, whh_t, W1_t, W2_t, Wq_t, Wk_b);
  k0_kernel<<<BB*4, 256, 0, stream>>>(slots_init, g_s, b_s, Wq_t, Wk_b, g_f, b_f,
                                      u_buf, su_buf, cb_buf);

  // iter 0
  phaseA_kernel<0,0><<<BB*NBLK, 256, 0, stream>>>(features, xb, stats, u_buf, su_buf, cb_buf,
                                                  P_part, S_part, R_part, out_attn);
  fusedB_kernel<0,1><<<BB*KS, 256, 0, stream>>>(P_part, S_part, R_part, slots_init, g_f, b_f,
                                                Wv_t, wih_t, whh_t, b_ih, b_hh, g_m, b_m,
                                                W1_t, b1, W2_t, b2, g_s, b_s, Wq_t, Wk_b,
                                                slots_ws, out_slots, u_buf, su_buf, cb_buf);
  // iter 1
  phaseA_kernel<1,0><<<BB*NBLK, 256, 0, stream>>>(features, xb, stats, u_buf, su_buf, cb_buf,
                                                  P_part, S_part, R_part, out_attn);
  fusedB_kernel<0,1><<<BB*KS, 256, 0, stream>>>(P_part, S_part, R_part, slots_ws, g_f, b_f,
                                                Wv_t, wih_t, whh_t, b_ih, b_hh, g_m, b_m,
                                                W1_t, b1, W2_t, b2, g_s, b_s, Wq_t, Wk_b,
                                                slots_ws, out_slots, u_buf, su_buf, cb_buf);
  // iter 2
  phaseA_kernel<1,1><<<BB*NBLK, 256, 0, stream>>>(features, xb, stats, u_buf, su_buf, cb_buf,
                                                  P_part, S_part, R_part, out_attn);
  fusedB_kernel<1,0><<<BB*KS, 256, 0, stream>>>(P_part, S_part, R_part, slots_ws, g_f, b_f,
                                                Wv_t, wih_t, whh_t, b_ih, b_hh, g_m, b_m,
                                                W1_t, b1, W2_t, b2, g_s, b_s, Wq_t, Wk_b,
                                                slots_ws, out_slots, u_buf, su_buf, cb_buf);
}